// Round 6
// baseline (453.413 us; speedup 1.0000x reference)
//
#include <hip/hip_runtime.h>
#include <hip/hip_bf16.h>
#include <hip/hip_fp16.h>

typedef __attribute__((ext_vector_type(4))) float f32x4;
typedef __attribute__((ext_vector_type(8))) _Float16 f16x8;
typedef __attribute__((ext_vector_type(4))) _Float16 f16x4;
typedef __attribute__((ext_vector_type(4))) int i32x4;

#define B_   8
#define S_   1024
#define H_   20
#define D_   64
#define E_   1280
#define QKV_ 3840
#define T_   8192

#define EXP2F(x) __builtin_amdgcn_exp2f(x)
#define QSCL 0.1803368801111204f   /* 0.125 * log2(e) */

__device__ __forceinline__ void gload_lds16(const void* g, void* l) {
    __builtin_amdgcn_global_load_lds((const __attribute__((address_space(1))) int*)g,
                                     (__attribute__((address_space(3))) int*)l, 16, 0, 0);
}

// ---------------- int32 -> int8 pack (values in [-127,127], exact) ----------------
__global__ __launch_bounds__(256) void cvt8_kernel(const int* __restrict__ in,
                                                   int* __restrict__ out, int n4) {
    int i = blockIdx.x * 256 + threadIdx.x;
    if (i >= n4) return;
    i32x4 v = ((const i32x4*)in)[i];
    out[i] = (v[0] & 255) | ((v[1] & 255) << 8) | ((v[2] & 255) << 16) | (v[3] << 24);
}

// ---------------- i8 GEMM: C[M,N] = A[M,K] * B[N,K]^T (i32 accum, exact) -------------
// 128x128 tile, BK=64 bytes, global_load_lds w16, XOR slot-swizzle (conflict-free),
// fused dequant epilogue. epilogue 0: scatter q/k (fp16 hi+lo, q pre-scaled) + v^T.
__global__ __launch_bounds__(256) void gemm_i8_kernel(
    const signed char* __restrict__ A, const signed char* __restrict__ Bw,
    int M, int N, int K,
    const float* __restrict__ rowscale, const float* __restrict__ colscale,
    const float* __restrict__ bias, int epilogue,
    __half* __restrict__ qh_out, __half* __restrict__ ql_out,
    __half* __restrict__ kh_out, __half* __restrict__ kl_out,
    __half* __restrict__ vt_out, float* __restrict__ out)
{
    __shared__ signed char As[128 * 64];
    __shared__ signed char Bs[128 * 64];

    const int tid  = threadIdx.x;
    const int lane = tid & 63;
    const int wave = tid >> 6;
    const int wm = wave >> 1, wn = wave & 1;          // 2x2 waves of 64x64
    const int nTn = N >> 7;
    const int nwg = (M >> 7) * nTn;                   // multiple of 8 for our shapes
    const int swz = (blockIdx.x & 7) * (nwg >> 3) + (blockIdx.x >> 3);
    const int tm = swz / nTn, tn = swz % nTn;

    i32x4 acc[4][4] = {};

    // staging: thread covers 16B; row rl, stored slot tid&3 holds global slot (tid&3)^w(rl)
    const int rl = tid >> 2;
    const int gs = (((tid & 3) ^ ((rl >> 1) & 3)) << 4);
    const size_t abase = (size_t)(tm * 128) * K;
    const size_t bbase = (size_t)(tn * 128) * K;

    const int fr = lane & 15;
    const int fg = lane >> 4;
    const int w4 = (fr >> 1) & 3;

    for (int k0 = 0; k0 < K; k0 += 64) {
        __syncthreads();
        gload_lds16(A  + abase + (size_t)rl        * K + k0 + gs, As + tid * 16);
        gload_lds16(A  + abase + (size_t)(rl + 64) * K + k0 + gs, As + (tid + 256) * 16);
        gload_lds16(Bw + bbase + (size_t)rl        * K + k0 + gs, Bs + tid * 16);
        gload_lds16(Bw + bbase + (size_t)(rl + 64) * K + k0 + gs, Bs + (tid + 256) * 16);
        __syncthreads();

        i32x4 af[4], bf[4];
#pragma unroll
        for (int m = 0; m < 4; ++m)
            af[m] = *(const i32x4*)&As[(wm * 64 + m * 16 + fr) * 64 + ((fg ^ w4) << 4)];
#pragma unroll
        for (int n = 0; n < 4; ++n)
            bf[n] = *(const i32x4*)&Bs[(wn * 64 + n * 16 + fr) * 64 + ((fg ^ w4) << 4)];
        __builtin_amdgcn_s_setprio(1);
#pragma unroll
        for (int m = 0; m < 4; ++m)
#pragma unroll
            for (int n = 0; n < 4; ++n)
                acc[m][n] = __builtin_amdgcn_mfma_i32_16x16x64_i8(af[m], bf[n], acc[m][n], 0, 0, 0);
        __builtin_amdgcn_s_setprio(0);
    }

    // epilogue: row = tm*128 + wm*64 + m*16 + fg*4 + r ; col = tn*128 + wn*64 + n*16 + fr
#pragma unroll
    for (int m = 0; m < 4; ++m) {
#pragma unroll
        for (int r = 0; r < 4; ++r) {
            const int grow = tm * 128 + wm * 64 + m * 16 + fg * 4 + r;
            const float rs = rowscale[grow];
#pragma unroll
            for (int n = 0; n < 4; ++n) {
                const int gcol = tn * 128 + wn * 64 + n * 16 + fr;
                const float v = (float)acc[m][n][r] * (rs * colscale[gcol]) + bias[gcol];
                if (epilogue == 0) {
                    const int b = grow >> 10, s = grow & 1023;
                    if (gcol < E_) {
                        const float vq = v * QSCL;          // fold softmax scale into q
                        const __half vh = (__half)vq;
                        const __half vl = (__half)(vq - (float)vh);
                        const int h = gcol >> 6, d = gcol & 63;
                        const size_t idx = (((size_t)(b * H_ + h) << 10) + s) * 64 + d;
                        qh_out[idx] = vh; ql_out[idx] = vl;
                    } else if (gcol < 2 * E_) {
                        const __half vh = (__half)v;
                        const __half vl = (__half)(v - (float)vh);
                        const int o = gcol - E_, h = o >> 6, d = o & 63;
                        const size_t idx = (((size_t)(b * H_ + h) << 10) + s) * 64 + d;
                        kh_out[idx] = vh; kl_out[idx] = vl;
                    } else {
                        const int o = gcol - 2 * E_, h = o >> 6, d = o & 63;
                        vt_out[(((size_t)(b * H_ + h) * 64 + d) << 10) + s] = (__half)v;
                    }
                } else {
                    out[(size_t)grow * E_ + gcol] = v;
                }
            }
        }
    }
}

// ---------------- flash attention: swapped QK^T, LDS Kh, global Kl, defer-max --------
__global__ __launch_bounds__(256) void attn_kernel(
    const __half* __restrict__ Qh, const __half* __restrict__ Ql,
    const __half* __restrict__ Kh, const __half* __restrict__ Kl,
    const __half* __restrict__ VT, __half* __restrict__ attn)
{
    __shared__ __half KhL[2][64 * 64];   // [buf][row*64 + col], XOR-swizzled 16B slots
    __shared__ __half Pl[4][16 * 72];    // per-wave P bounce, stride 144B

    const int tid = threadIdx.x, lane = tid & 63, wave = tid >> 6;
    // XCD-clustered bijective remap: xcd = L&7 gets 20 contiguous heads
    const int L = blockIdx.x;
    const int sIdx = L >> 3;
    const int bh = (L & 7) * 20 + (sIdx >> 4);
    const int qt = sIdx & 15;
    const int b = bh / H_, h = bh % H_;
    const int q0 = qt * 64 + wave * 16;
    const size_t base_sd = (size_t)bh * S_ * D_;
    const size_t base_ds = (size_t)bh * D_ * S_;
    const int fr = lane & 15, fg = lane >> 4;

    f16x8 qh0 = *(const f16x8*)&Qh[base_sd + (size_t)(q0 + fr) * 64 +      fg * 8];
    f16x8 qh1 = *(const f16x8*)&Qh[base_sd + (size_t)(q0 + fr) * 64 + 32 + fg * 8];
    f16x8 ql0 = *(const f16x8*)&Ql[base_sd + (size_t)(q0 + fr) * 64 +      fg * 8];
    f16x8 ql1 = *(const f16x8*)&Ql[base_sd + (size_t)(q0 + fr) * 64 + 32 + fg * 8];

    f32x4 o[4] = {};
    float mrow = -INFINITY, lrow = 0.f;   // per-lane: ONE q-row (q0 + fr)

#define STAGEK(bf, kt) do {                                                   \
    _Pragma("unroll")                                                         \
    for (int c_ = 0; c_ < 2; ++c_) {                                          \
        const int qb_ = wave * 2048 + c_ * 1024 + lane * 16;                  \
        const int row_ = qb_ >> 7, cb_ = qb_ & 127;                           \
        const int scb_ = cb_ ^ ((row_ & 7) << 4);                             \
        gload_lds16((const char*)(Kh + base_sd) + (size_t)((kt) + row_) * 128 + scb_, \
                    (char*)&KhL[bf][0] + qb_);                                \
    }                                                                         \
} while (0)

    STAGEK(0, 0);
    __syncthreads();

    for (int it = 0; it < 16; ++it) {
        const int kt = it * 64;
        const int bf = it & 1;

        // VT + Kl loads early (global; latency hidden under QK)
        f16x8 vf[4][2];
#pragma unroll
        for (int dc = 0; dc < 4; ++dc) {
            const size_t vb = base_ds + (size_t)(dc * 16 + fr) * S_ + kt + fg * 8;
            vf[dc][0] = *(const f16x8*)&VT[vb];
            vf[dc][1] = *(const f16x8*)&VT[vb + 32];
        }
        f16x8 kl0[4], kl1[4];
#pragma unroll
        for (int t = 0; t < 4; ++t) {
            const size_t kb = base_sd + (size_t)(kt + t * 16 + fr) * 64 + fg * 8;
            kl0[t] = *(const f16x8*)&Kl[kb];
            kl1[t] = *(const f16x8*)&Kl[kb + 32];
        }
        if (it < 15) STAGEK(bf ^ 1, kt + 64);

        // swapped QK^T: st[t] = S^T tile; lane: q = q0+fr, k = kt + t*16 + fg*4 + r
        f32x4 st[4] = {};
        __builtin_amdgcn_s_setprio(1);
#pragma unroll
        for (int t = 0; t < 4; ++t) {
            const int rowb = (t * 16 + fr) * 128;
            const int c0 = (fg * 16)      ^ ((fr & 7) << 4);
            const int c1 = (64 + fg * 16) ^ ((fr & 7) << 4);
            f16x8 a0 = *(const f16x8*)((const char*)&KhL[bf][0] + rowb + c0);
            f16x8 a1 = *(const f16x8*)((const char*)&KhL[bf][0] + rowb + c1);
            st[t] = __builtin_amdgcn_mfma_f32_16x16x32_f16(a0, qh0, st[t], 0, 0, 0);
            st[t] = __builtin_amdgcn_mfma_f32_16x16x32_f16(a1, qh1, st[t], 0, 0, 0);
            st[t] = __builtin_amdgcn_mfma_f32_16x16x32_f16(a0, ql0, st[t], 0, 0, 0);
            st[t] = __builtin_amdgcn_mfma_f32_16x16x32_f16(a1, ql1, st[t], 0, 0, 0);
            st[t] = __builtin_amdgcn_mfma_f32_16x16x32_f16(kl0[t], qh0, st[t], 0, 0, 0);
            st[t] = __builtin_amdgcn_mfma_f32_16x16x32_f16(kl1[t], qh1, st[t], 0, 0, 0);
        }
        __builtin_amdgcn_s_setprio(0);

        // softmax over 64 kv: in-lane 16 + xor16 + xor32
        float mt0 = fmaxf(fmaxf(st[0][0], st[0][1]), fmaxf(st[0][2], st[0][3]));
        float mt1 = fmaxf(fmaxf(st[1][0], st[1][1]), fmaxf(st[1][2], st[1][3]));
        float mt2 = fmaxf(fmaxf(st[2][0], st[2][1]), fmaxf(st[2][2], st[2][3]));
        float mt3 = fmaxf(fmaxf(st[3][0], st[3][1]), fmaxf(st[3][2], st[3][3]));
        float mx = fmaxf(fmaxf(mt0, mt1), fmaxf(mt2, mt3));
        mx = fmaxf(mx, __shfl_xor(mx, 16));
        mx = fmaxf(mx, __shfl_xor(mx, 32));

        // defer-max (T13): skip o-rescale unless some row grew by > 8 (exp2 domain)
        if (!__all(mx - mrow <= 8.f)) {
            const float mn = fmaxf(mrow, mx);
            const float fsc = EXP2F(mrow - mn);   // exp2(-inf)=0 on first tile
            mrow = mn;
            lrow *= fsc;
            float fscr[4];
#pragma unroll
            for (int r = 0; r < 4; ++r) fscr[r] = __shfl(fsc, ((lane >> 4) << 2) + r);
#pragma unroll
            for (int dc = 0; dc < 4; ++dc)
#pragma unroll
                for (int r = 0; r < 4; ++r) o[dc][r] *= fscr[r];
        }

        float p[4][4];
        float rsum = 0.f;
#pragma unroll
        for (int t = 0; t < 4; ++t) {
            p[t][0] = EXP2F(st[t][0] - mrow);
            p[t][1] = EXP2F(st[t][1] - mrow);
            p[t][2] = EXP2F(st[t][2] - mrow);
            p[t][3] = EXP2F(st[t][3] - mrow);
            rsum += (p[t][0] + p[t][1]) + (p[t][2] + p[t][3]);
        }
        rsum += __shfl_xor(rsum, 16);
        rsum += __shfl_xor(rsum, 32);
        lrow += rsum;

        // P -> LDS bounce (transpose to A-frag layout)
#pragma unroll
        for (int t = 0; t < 4; ++t) {
            f16x4 pk;
            pk[0] = (_Float16)p[t][0]; pk[1] = (_Float16)p[t][1];
            pk[2] = (_Float16)p[t][2]; pk[3] = (_Float16)p[t][3];
            *(f16x4*)((char*)&Pl[wave][0] + fr * 144 + t * 32 + fg * 8) = pk;
        }
        asm volatile("s_waitcnt lgkmcnt(0)" ::: "memory");
        __builtin_amdgcn_sched_barrier(0);
        f16x8 pf0 = *(const f16x8*)((const char*)&Pl[wave][0] + fr * 144 +      fg * 16);
        f16x8 pf1 = *(const f16x8*)((const char*)&Pl[wave][0] + fr * 144 + 64 + fg * 16);
        __builtin_amdgcn_s_setprio(1);
#pragma unroll
        for (int dc = 0; dc < 4; ++dc) {
            o[dc] = __builtin_amdgcn_mfma_f32_16x16x32_f16(pf0, vf[dc][0], o[dc], 0, 0, 0);
            o[dc] = __builtin_amdgcn_mfma_f32_16x16x32_f16(pf1, vf[dc][1], o[dc], 0, 0, 0);
        }
        __builtin_amdgcn_s_setprio(0);
        __syncthreads();
    }

    float lrowr[4];
#pragma unroll
    for (int r = 0; r < 4; ++r) lrowr[r] = __shfl(lrow, ((lane >> 4) << 2) + r);
#pragma unroll
    for (int dc = 0; dc < 4; ++dc)
#pragma unroll
        for (int r = 0; r < 4; ++r) {
            const int t = (b << 10) + q0 + fg * 4 + r;
            attn[(size_t)t * E_ + h * 64 + dc * 16 + fr] = (__half)(o[dc][r] / lrowr[r]);
        }
#undef STAGEK
}

// ---------------- per-token symmetric int8 requant (int8 output for i8 GEMM) ---------
__global__ __launch_bounds__(256) void requant_kernel(
    const __half* __restrict__ attn, signed char* __restrict__ aq, float* __restrict__ as_)
{
    const int t = blockIdx.x;
    const int tid = threadIdx.x;
    __shared__ float red[4];
    const __half* row = attn + (size_t)t * E_;
    float x[5];
    float amax = 0.f;
#pragma unroll
    for (int j = 0; j < 5; ++j) {
        x[j] = (float)row[tid + j * 256];
        amax = fmaxf(amax, fabsf(x[j]));
    }
#pragma unroll
    for (int off = 1; off < 64; off <<= 1) amax = fmaxf(amax, __shfl_xor(amax, off));
    if ((tid & 63) == 0) red[tid >> 6] = amax;
    __syncthreads();
    amax = fmaxf(fmaxf(red[0], red[1]), fmaxf(red[2], red[3]));
    const float s = fmaxf(amax / 127.f, 1e-8f);
    if (tid == 0) as_[t] = s;
#pragma unroll
    for (int j = 0; j < 5; ++j) {
        float qv = fminf(fmaxf(rintf(x[j] / s), -127.f), 127.f);
        aq[(size_t)t * E_ + tid + j * 256] = (signed char)(int)qv;
    }
}

// ---------------- launch ----------------
extern "C" void kernel_launch(void* const* d_in, const int* in_sizes, int n_in,
                              void* d_out, int out_size, void* d_ws, size_t ws_size,
                              hipStream_t stream) {
    const int*   x_q         = (const int*)d_in[0];
    const float* in_scale    = (const float*)d_in[1];
    const int*   w_qkv       = (const int*)d_in[2];
    const float* w_qkv_scale = (const float*)d_in[3];
    const float* b_qkv       = (const float*)d_in[4];
    const int*   w_out       = (const int*)d_in[5];
    const float* w_out_scale = (const float*)d_in[6];
    const float* b_out       = (const float*)d_in[7];
    float* out = (float*)d_out;

    char* ws = (char*)d_ws;
    signed char* x_i8  = (signed char*)(ws);                 // 10,485,760 (dead after GEMM1)
    signed char* wq_i8 = (signed char*)(ws + 10485760);      //  4,915,200 (dead after GEMM1)
    __half* attn_f     = (__half*)(ws);                      // 20,971,520 (overlays x+wq)
    signed char* wo_i8 = (signed char*)(ws + 20971520);      //  1,638,400 (live till GEMM2)
    float*  a_s        = (float*)(ws + 22609920);            //     32,768
    __half* qh_f       = (__half*)(ws + 22642688);           // 20,971,520 [B,H,S,D]
    __half* ql_f       = (__half*)(ws + 43614208);           // 20,971,520
    __half* kh_f       = (__half*)(ws + 64585728);           // 20,971,520
    __half* kl_f       = (__half*)(ws + 85557248);           // 20,971,520
    __half* vt_f       = (__half*)(ws + 106528768);          // 20,971,520 [B,H,D,S]
    signed char* aq_i8 = (signed char*)(ws + 22642688);      // 10,485,760 (overlays qh_f)

    cvt8_kernel<<<(T_ * E_ / 4 + 255) / 256, 256, 0, stream>>>(x_q, (int*)x_i8, T_ * E_ / 4);
    cvt8_kernel<<<(QKV_ * E_ / 4 + 255) / 256, 256, 0, stream>>>(w_qkv, (int*)wq_i8, QKV_ * E_ / 4);
    cvt8_kernel<<<(E_ * E_ / 4 + 255) / 256, 256, 0, stream>>>(w_out, (int*)wo_i8, E_ * E_ / 4);

    gemm_i8_kernel<<<(T_ / 128) * (QKV_ / 128), 256, 0, stream>>>(
        x_i8, wq_i8, T_, QKV_, E_, in_scale, w_qkv_scale, b_qkv, 0,
        qh_f, ql_f, kh_f, kl_f, vt_f, nullptr);

    attn_kernel<<<B_ * H_ * (S_ / 64), 256, 0, stream>>>(qh_f, ql_f, kh_f, kl_f, vt_f, attn_f);

    requant_kernel<<<T_, 256, 0, stream>>>(attn_f, aq_i8, a_s);

    gemm_i8_kernel<<<(T_ / 128) * (E_ / 128), 256, 0, stream>>>(
        aq_i8, wo_i8, T_, E_, E_, a_s, w_out_scale, b_out, 1,
        nullptr, nullptr, nullptr, nullptr, nullptr, out);
}

// Round 7
// 329.941 us; speedup vs baseline: 1.3742x; 1.3742x over previous
//
#include <hip/hip_runtime.h>
#include <hip/hip_bf16.h>
#include <hip/hip_fp16.h>

typedef __attribute__((ext_vector_type(4))) float f32x4;
typedef __attribute__((ext_vector_type(8))) _Float16 f16x8;
typedef __attribute__((ext_vector_type(4))) _Float16 f16x4;
typedef __attribute__((ext_vector_type(4))) int i32x4;

#define B_   8
#define S_   1024
#define H_   20
#define D_   64
#define E_   1280
#define QKV_ 3840
#define T_   8192

#define EXP2F(x) __builtin_amdgcn_exp2f(x)
#define QSCL 0.1803368801111204f   /* 0.125 * log2(e) */

__device__ __forceinline__ void gload_lds16(const void* g, void* l) {
    __builtin_amdgcn_global_load_lds((const __attribute__((address_space(1))) int*)g,
                                     (__attribute__((address_space(3))) int*)l, 16, 0, 0);
}

// ---------------- int32 -> int8 pack (values in [-127,127], exact) ----------------
__global__ __launch_bounds__(256) void cvt8_kernel(const int* __restrict__ in,
                                                   int* __restrict__ out, int n4) {
    int i = blockIdx.x * 256 + threadIdx.x;
    if (i >= n4) return;
    i32x4 v = ((const i32x4*)in)[i];
    out[i] = (v[0] & 255) | ((v[1] & 255) << 8) | ((v[2] & 255) << 16) | (v[3] << 24);
}

// ---------------- i8 GEMM: C[M,N] = A[M,K] * B[N,K]^T (i32 accum, exact) -------------
__global__ __launch_bounds__(256) void gemm_i8_kernel(
    const signed char* __restrict__ A, const signed char* __restrict__ Bw,
    int M, int N, int K,
    const float* __restrict__ rowscale, const float* __restrict__ colscale,
    const float* __restrict__ bias, int epilogue,
    __half* __restrict__ qh_out, __half* __restrict__ ql_out,
    __half* __restrict__ kh_out, __half* __restrict__ kl_out,
    __half* __restrict__ vt_out, float* __restrict__ out)
{
    __shared__ signed char As[128 * 64];
    __shared__ signed char Bs[128 * 64];

    const int tid  = threadIdx.x;
    const int lane = tid & 63;
    const int wave = tid >> 6;
    const int wm = wave >> 1, wn = wave & 1;          // 2x2 waves of 64x64
    const int nTn = N >> 7;
    const int nwg = (M >> 7) * nTn;                   // multiple of 8 for our shapes
    const int swz = (blockIdx.x & 7) * (nwg >> 3) + (blockIdx.x >> 3);
    const int tm = swz / nTn, tn = swz % nTn;

    i32x4 acc[4][4] = {};

    // staging: thread covers 16B; row rl, stored slot tid&3 holds global slot (tid&3)^w(rl)
    const int rl = tid >> 2;
    const int gs = (((tid & 3) ^ ((rl >> 1) & 3)) << 4);
    const size_t abase = (size_t)(tm * 128) * K;
    const size_t bbase = (size_t)(tn * 128) * K;

    const int fr = lane & 15;
    const int fg = lane >> 4;
    const int w4 = (fr >> 1) & 3;

    for (int k0 = 0; k0 < K; k0 += 64) {
        __syncthreads();
        gload_lds16(A  + abase + (size_t)rl        * K + k0 + gs, As + tid * 16);
        gload_lds16(A  + abase + (size_t)(rl + 64) * K + k0 + gs, As + (tid + 256) * 16);
        gload_lds16(Bw + bbase + (size_t)rl        * K + k0 + gs, Bs + tid * 16);
        gload_lds16(Bw + bbase + (size_t)(rl + 64) * K + k0 + gs, Bs + (tid + 256) * 16);
        __syncthreads();

        i32x4 af[4], bf[4];
#pragma unroll
        for (int m = 0; m < 4; ++m)
            af[m] = *(const i32x4*)&As[(wm * 64 + m * 16 + fr) * 64 + ((fg ^ w4) << 4)];
#pragma unroll
        for (int n = 0; n < 4; ++n)
            bf[n] = *(const i32x4*)&Bs[(wn * 64 + n * 16 + fr) * 64 + ((fg ^ w4) << 4)];
        __builtin_amdgcn_s_setprio(1);
#pragma unroll
        for (int m = 0; m < 4; ++m)
#pragma unroll
            for (int n = 0; n < 4; ++n)
                acc[m][n] = __builtin_amdgcn_mfma_i32_16x16x64_i8(af[m], bf[n], acc[m][n], 0, 0, 0);
        __builtin_amdgcn_s_setprio(0);
    }

    // epilogue: row = tm*128 + wm*64 + m*16 + fg*4 + r ; col = tn*128 + wn*64 + n*16 + fr
#pragma unroll
    for (int m = 0; m < 4; ++m) {
#pragma unroll
        for (int r = 0; r < 4; ++r) {
            const int grow = tm * 128 + wm * 64 + m * 16 + fg * 4 + r;
            const float rs = rowscale[grow];
#pragma unroll
            for (int n = 0; n < 4; ++n) {
                const int gcol = tn * 128 + wn * 64 + n * 16 + fr;
                const float v = (float)acc[m][n][r] * (rs * colscale[gcol]) + bias[gcol];
                if (epilogue == 0) {
                    const int b = grow >> 10, s = grow & 1023;
                    if (gcol < E_) {
                        const float vq = v * QSCL;          // fold softmax scale into q
                        const __half vh = (__half)vq;
                        const __half vl = (__half)(vq - (float)vh);
                        const int h = gcol >> 6, d = gcol & 63;
                        const size_t idx = (((size_t)(b * H_ + h) << 10) + s) * 64 + d;
                        qh_out[idx] = vh; ql_out[idx] = vl;
                    } else if (gcol < 2 * E_) {
                        const __half vh = (__half)v;
                        const __half vl = (__half)(v - (float)vh);
                        const int o = gcol - E_, h = o >> 6, d = o & 63;
                        const size_t idx = (((size_t)(b * H_ + h) << 10) + s) * 64 + d;
                        kh_out[idx] = vh; kl_out[idx] = vl;
                    } else {
                        const int o = gcol - 2 * E_, h = o >> 6, d = o & 63;
                        vt_out[(((size_t)(b * H_ + h) * 64 + d) << 10) + s] = (__half)v;
                    }
                } else {
                    out[(size_t)grow * E_ + gcol] = v;
                }
            }
        }
    }
}

// ---------------- flash attention: swapped QK^T, LDS Kh+Kl dbuf, defer-max -----------
// grid: 2560 blocks (XCD-clustered remap); 4 waves/block, each wave owns 16 q-rows.
__global__ __launch_bounds__(256) void attn_kernel(
    const __half* __restrict__ Qh, const __half* __restrict__ Ql,
    const __half* __restrict__ Kh, const __half* __restrict__ Kl,
    const __half* __restrict__ VT, __half* __restrict__ attn)
{
    __shared__ __half KhL[2][64 * 64];   // [buf][row*64 + col], XOR-swizzled 16B slots
    __shared__ __half KlL[2][64 * 64];
    __shared__ __half Pl[4][16 * 72];    // per-wave P bounce, stride 144B

    const int tid = threadIdx.x, lane = tid & 63, wave = tid >> 6;
    // XCD-clustered bijective remap: xcd = L&7 gets 20 contiguous heads
    const int L = blockIdx.x;
    const int sIdx = L >> 3;
    const int bh = (L & 7) * 20 + (sIdx >> 4);
    const int qt = sIdx & 15;
    const int b = bh / H_, h = bh % H_;
    const int q0 = qt * 64 + wave * 16;
    const size_t base_sd = (size_t)bh * S_ * D_;
    const size_t base_ds = (size_t)bh * D_ * S_;
    const int fr = lane & 15, fg = lane >> 4;

    f16x8 qh0 = *(const f16x8*)&Qh[base_sd + (size_t)(q0 + fr) * 64 +      fg * 8];
    f16x8 qh1 = *(const f16x8*)&Qh[base_sd + (size_t)(q0 + fr) * 64 + 32 + fg * 8];
    f16x8 ql0 = *(const f16x8*)&Ql[base_sd + (size_t)(q0 + fr) * 64 +      fg * 8];
    f16x8 ql1 = *(const f16x8*)&Ql[base_sd + (size_t)(q0 + fr) * 64 + 32 + fg * 8];

    f32x4 o[4] = {};
    float mrow = -INFINITY, lrow = 0.f;   // per-lane: ONE q-row (q0 + fr)

    // stage K chunk into buf bf: linear LDS dest, inverse-swizzled global source
#define STAGEK(bf, kt) do {                                                   \
    _Pragma("unroll")                                                         \
    for (int c_ = 0; c_ < 2; ++c_) {                                          \
        const int qb_ = wave * 2048 + c_ * 1024 + lane * 16;                  \
        const int row_ = qb_ >> 7, cb_ = qb_ & 127;                           \
        const int scb_ = cb_ ^ ((row_ & 7) << 4);                             \
        gload_lds16((const char*)(Kh + base_sd) + (size_t)((kt) + row_) * 128 + scb_, \
                    (char*)&KhL[bf][0] + qb_);                                \
        gload_lds16((const char*)(Kl + base_sd) + (size_t)((kt) + row_) * 128 + scb_, \
                    (char*)&KlL[bf][0] + qb_);                                \
    }                                                                         \
} while (0)

    STAGEK(0, 0);
    __syncthreads();

    for (int it = 0; it < 16; ++it) {
        const int kt = it * 64;
        const int bf = it & 1;

        // VT loads early (global), consumed by PV at phase end -> latency hidden
        f16x8 vf[4][2];
#pragma unroll
        for (int dc = 0; dc < 4; ++dc) {
            const size_t vb = base_ds + (size_t)(dc * 16 + fr) * S_ + kt + fg * 8;
            vf[dc][0] = *(const f16x8*)&VT[vb];
            vf[dc][1] = *(const f16x8*)&VT[vb + 32];
        }
        if (it < 15) STAGEK(bf ^ 1, kt + 64);

        // swapped QK^T: st[t] = S^T tile; lane: q = q0+fr, k = kt + t*16 + fg*4 + r
        f32x4 st[4] = {};
        __builtin_amdgcn_s_setprio(1);
#pragma unroll
        for (int t = 0; t < 4; ++t) {
            const int rowb = (t * 16 + fr) * 128;
            const int c0 = (fg * 16)      ^ ((fr & 7) << 4);
            const int c1 = (64 + fg * 16) ^ ((fr & 7) << 4);
            f16x8 a0 = *(const f16x8*)((const char*)&KhL[bf][0] + rowb + c0);
            f16x8 a1 = *(const f16x8*)((const char*)&KhL[bf][0] + rowb + c1);
            f16x8 e0 = *(const f16x8*)((const char*)&KlL[bf][0] + rowb + c0);
            f16x8 e1 = *(const f16x8*)((const char*)&KlL[bf][0] + rowb + c1);
            st[t] = __builtin_amdgcn_mfma_f32_16x16x32_f16(a0, qh0, st[t], 0, 0, 0);
            st[t] = __builtin_amdgcn_mfma_f32_16x16x32_f16(a1, qh1, st[t], 0, 0, 0);
            st[t] = __builtin_amdgcn_mfma_f32_16x16x32_f16(a0, ql0, st[t], 0, 0, 0);
            st[t] = __builtin_amdgcn_mfma_f32_16x16x32_f16(a1, ql1, st[t], 0, 0, 0);
            st[t] = __builtin_amdgcn_mfma_f32_16x16x32_f16(e0, qh0, st[t], 0, 0, 0);
            st[t] = __builtin_amdgcn_mfma_f32_16x16x32_f16(e1, qh1, st[t], 0, 0, 0);
        }
        __builtin_amdgcn_s_setprio(0);

        // softmax over 64 kv: in-lane 16 + xor16 + xor32
        float mt0 = fmaxf(fmaxf(st[0][0], st[0][1]), fmaxf(st[0][2], st[0][3]));
        float mt1 = fmaxf(fmaxf(st[1][0], st[1][1]), fmaxf(st[1][2], st[1][3]));
        float mt2 = fmaxf(fmaxf(st[2][0], st[2][1]), fmaxf(st[2][2], st[2][3]));
        float mt3 = fmaxf(fmaxf(st[3][0], st[3][1]), fmaxf(st[3][2], st[3][3]));
        float mx = fmaxf(fmaxf(mt0, mt1), fmaxf(mt2, mt3));
        mx = fmaxf(mx, __shfl_xor(mx, 16));
        mx = fmaxf(mx, __shfl_xor(mx, 32));

        // defer-max (T13): skip o-rescale unless some row grew by > 8 (exp2 domain)
        if (!__all(mx - mrow <= 8.f)) {
            const float mn = fmaxf(mrow, mx);
            const float fsc = EXP2F(mrow - mn);   // exp2(-inf)=0 on first tile
            mrow = mn;
            lrow *= fsc;
            float fscr[4];
#pragma unroll
            for (int r = 0; r < 4; ++r) fscr[r] = __shfl(fsc, ((lane >> 4) << 2) + r);
#pragma unroll
            for (int dc = 0; dc < 4; ++dc)
#pragma unroll
                for (int r = 0; r < 4; ++r) o[dc][r] *= fscr[r];
        }

        float p[4][4];
        float rsum = 0.f;
#pragma unroll
        for (int t = 0; t < 4; ++t) {
            p[t][0] = EXP2F(st[t][0] - mrow);
            p[t][1] = EXP2F(st[t][1] - mrow);
            p[t][2] = EXP2F(st[t][2] - mrow);
            p[t][3] = EXP2F(st[t][3] - mrow);
            rsum += (p[t][0] + p[t][1]) + (p[t][2] + p[t][3]);
        }
        rsum += __shfl_xor(rsum, 16);
        rsum += __shfl_xor(rsum, 32);
        lrow += rsum;

        // P -> LDS bounce (transpose to A-frag layout)
#pragma unroll
        for (int t = 0; t < 4; ++t) {
            f16x4 pk;
            pk[0] = (_Float16)p[t][0]; pk[1] = (_Float16)p[t][1];
            pk[2] = (_Float16)p[t][2]; pk[3] = (_Float16)p[t][3];
            *(f16x4*)((char*)&Pl[wave][0] + fr * 144 + t * 32 + fg * 8) = pk;
        }
        asm volatile("s_waitcnt lgkmcnt(0)" ::: "memory");
        __builtin_amdgcn_sched_barrier(0);
        f16x8 pf0 = *(const f16x8*)((const char*)&Pl[wave][0] + fr * 144 +      fg * 16);
        f16x8 pf1 = *(const f16x8*)((const char*)&Pl[wave][0] + fr * 144 + 64 + fg * 16);
        __builtin_amdgcn_s_setprio(1);
#pragma unroll
        for (int dc = 0; dc < 4; ++dc) {
            o[dc] = __builtin_amdgcn_mfma_f32_16x16x32_f16(pf0, vf[dc][0], o[dc], 0, 0, 0);
            o[dc] = __builtin_amdgcn_mfma_f32_16x16x32_f16(pf1, vf[dc][1], o[dc], 0, 0, 0);
        }
        __builtin_amdgcn_s_setprio(0);
        __syncthreads();
    }

    float lrowr[4];
#pragma unroll
    for (int r = 0; r < 4; ++r) lrowr[r] = __shfl(lrow, ((lane >> 4) << 2) + r);
#pragma unroll
    for (int dc = 0; dc < 4; ++dc)
#pragma unroll
        for (int r = 0; r < 4; ++r) {
            const int t = (b << 10) + q0 + fg * 4 + r;
            attn[(size_t)t * E_ + h * 64 + dc * 16 + fr] = (__half)(o[dc][r] / lrowr[r]);
        }
#undef STAGEK
}

// ---------------- per-token symmetric int8 requant (int8 output for i8 GEMM) ---------
__global__ __launch_bounds__(256) void requant_kernel(
    const __half* __restrict__ attn, signed char* __restrict__ aq, float* __restrict__ as_)
{
    const int t = blockIdx.x;
    const int tid = threadIdx.x;
    __shared__ float red[4];
    const __half* row = attn + (size_t)t * E_;
    float x[5];
    float amax = 0.f;
#pragma unroll
    for (int j = 0; j < 5; ++j) {
        x[j] = (float)row[tid + j * 256];
        amax = fmaxf(amax, fabsf(x[j]));
    }
#pragma unroll
    for (int off = 1; off < 64; off <<= 1) amax = fmaxf(amax, __shfl_xor(amax, off));
    if ((tid & 63) == 0) red[tid >> 6] = amax;
    __syncthreads();
    amax = fmaxf(fmaxf(red[0], red[1]), fmaxf(red[2], red[3]));
    const float s = fmaxf(amax / 127.f, 1e-8f);
    if (tid == 0) as_[t] = s;
#pragma unroll
    for (int j = 0; j < 5; ++j) {
        float qv = fminf(fmaxf(rintf(x[j] / s), -127.f), 127.f);
        aq[(size_t)t * E_ + tid + j * 256] = (signed char)(int)qv;
    }
}

// ---------------- launch ----------------
extern "C" void kernel_launch(void* const* d_in, const int* in_sizes, int n_in,
                              void* d_out, int out_size, void* d_ws, size_t ws_size,
                              hipStream_t stream) {
    const int*   x_q         = (const int*)d_in[0];
    const float* in_scale    = (const float*)d_in[1];
    const int*   w_qkv       = (const int*)d_in[2];
    const float* w_qkv_scale = (const float*)d_in[3];
    const float* b_qkv       = (const float*)d_in[4];
    const int*   w_out       = (const int*)d_in[5];
    const float* w_out_scale = (const float*)d_in[6];
    const float* b_out       = (const float*)d_in[7];
    float* out = (float*)d_out;

    char* ws = (char*)d_ws;
    signed char* x_i8  = (signed char*)(ws);                 // 10,485,760 (dead after GEMM1)
    signed char* wq_i8 = (signed char*)(ws + 10485760);      //  4,915,200 (dead after GEMM1)
    __half* attn_f     = (__half*)(ws);                      // 20,971,520 (overlays x+wq)
    signed char* wo_i8 = (signed char*)(ws + 20971520);      //  1,638,400 (live till GEMM2)
    float*  a_s        = (float*)(ws + 22609920);            //     32,768
    __half* qh_f       = (__half*)(ws + 22642688);           // 20,971,520 [B,H,S,D]
    __half* ql_f       = (__half*)(ws + 43614208);           // 20,971,520
    __half* kh_f       = (__half*)(ws + 64585728);           // 20,971,520
    __half* kl_f       = (__half*)(ws + 85557248);           // 20,971,520
    __half* vt_f       = (__half*)(ws + 106528768);          // 20,971,520 [B,H,D,S]
    signed char* aq_i8 = (signed char*)(ws + 22642688);      // 10,485,760 (overlays qh_f)

    cvt8_kernel<<<(T_ * E_ / 4 + 255) / 256, 256, 0, stream>>>(x_q, (int*)x_i8, T_ * E_ / 4);
    cvt8_kernel<<<(QKV_ * E_ / 4 + 255) / 256, 256, 0, stream>>>(w_qkv, (int*)wq_i8, QKV_ * E_ / 4);
    cvt8_kernel<<<(E_ * E_ / 4 + 255) / 256, 256, 0, stream>>>(w_out, (int*)wo_i8, E_ * E_ / 4);

    gemm_i8_kernel<<<(T_ / 128) * (QKV_ / 128), 256, 0, stream>>>(
        x_i8, wq_i8, T_, QKV_, E_, in_scale, w_qkv_scale, b_qkv, 0,
        qh_f, ql_f, kh_f, kl_f, vt_f, nullptr);

    attn_kernel<<<B_ * H_ * (S_ / 64), 256, 0, stream>>>(qh_f, ql_f, kh_f, kl_f, vt_f, attn_f);

    requant_kernel<<<T_, 256, 0, stream>>>(attn_f, aq_i8, a_s);

    gemm_i8_kernel<<<(T_ / 128) * (E_ / 128), 256, 0, stream>>>(
        aq_i8, wo_i8, T_, E_, E_, a_s, w_out_scale, b_out, 1,
        nullptr, nullptr, nullptr, nullptr, nullptr, out);
}

// Round 8
// 320.440 us; speedup vs baseline: 1.4150x; 1.0297x over previous
//
#include <hip/hip_runtime.h>
#include <hip/hip_bf16.h>
#include <hip/hip_fp16.h>

typedef __attribute__((ext_vector_type(4))) float f32x4;
typedef __attribute__((ext_vector_type(8))) _Float16 f16x8;
typedef __attribute__((ext_vector_type(4))) _Float16 f16x4;
typedef __attribute__((ext_vector_type(4))) int i32x4;

#define B_   8
#define S_   1024
#define H_   20
#define D_   64
#define E_   1280
#define QKV_ 3840
#define T_   8192

#define EXP2F(x) __builtin_amdgcn_exp2f(x)
#define QSCL 0.1803368801111204f   /* 0.125 * log2(e) */

__device__ __forceinline__ void gload_lds16(const void* g, void* l) {
    __builtin_amdgcn_global_load_lds((const __attribute__((address_space(1))) int*)g,
                                     (__attribute__((address_space(3))) int*)l, 16, 0, 0);
}

// ---------------- int32 -> int8 pack, 3 tensors in one launch ----------------
#define NX4 (T_ * E_ / 4)
#define NQ4 (QKV_ * E_ / 4)
#define NO4 (E_ * E_ / 4)
__global__ __launch_bounds__(256) void cvt8_all_kernel(
    const int* __restrict__ x, const int* __restrict__ wq, const int* __restrict__ wo,
    int* __restrict__ xo, int* __restrict__ wqo, int* __restrict__ woo) {
    int i = blockIdx.x * 256 + threadIdx.x;
    const int* src; int* dst; int idx;
    if (i < NX4)              { src = x;  dst = xo;  idx = i; }
    else if (i < NX4 + NQ4)   { src = wq; dst = wqo; idx = i - NX4; }
    else if (i < NX4+NQ4+NO4) { src = wo; dst = woo; idx = i - NX4 - NQ4; }
    else return;
    i32x4 v = ((const i32x4*)src)[idx];
    dst[idx] = (v[0] & 255) | ((v[1] & 255) << 8) | ((v[2] & 255) << 16) | (v[3] << 24);
}

// ---------------- i8 GEMM: C[M,N] = A[M,K] * B[N,K]^T (i32 accum, exact) -------------
__global__ __launch_bounds__(256) void gemm_i8_kernel(
    const signed char* __restrict__ A, const signed char* __restrict__ Bw,
    int M, int N, int K,
    const float* __restrict__ rowscale, const float* __restrict__ colscale,
    const float* __restrict__ bias, int epilogue,
    __half* __restrict__ qh_out, __half* __restrict__ ql_out,
    __half* __restrict__ kh_out, __half* __restrict__ kl_out,
    __half* __restrict__ vt_out, float* __restrict__ out)
{
    __shared__ signed char As[128 * 64];
    __shared__ signed char Bs[128 * 64];

    const int tid  = threadIdx.x;
    const int lane = tid & 63;
    const int wave = tid >> 6;
    const int wm = wave >> 1, wn = wave & 1;          // 2x2 waves of 64x64
    const int nTn = N >> 7;
    const int nwg = (M >> 7) * nTn;                   // multiple of 8 for our shapes
    const int swz = (blockIdx.x & 7) * (nwg >> 3) + (blockIdx.x >> 3);
    const int tm = swz / nTn, tn = swz % nTn;

    i32x4 acc[4][4] = {};

    const int rl = tid >> 2;
    const int gs = (((tid & 3) ^ ((rl >> 1) & 3)) << 4);
    const size_t abase = (size_t)(tm * 128) * K;
    const size_t bbase = (size_t)(tn * 128) * K;

    const int fr = lane & 15;
    const int fg = lane >> 4;
    const int w4 = (fr >> 1) & 3;

    for (int k0 = 0; k0 < K; k0 += 64) {
        __syncthreads();
        gload_lds16(A  + abase + (size_t)rl        * K + k0 + gs, As + tid * 16);
        gload_lds16(A  + abase + (size_t)(rl + 64) * K + k0 + gs, As + (tid + 256) * 16);
        gload_lds16(Bw + bbase + (size_t)rl        * K + k0 + gs, Bs + tid * 16);
        gload_lds16(Bw + bbase + (size_t)(rl + 64) * K + k0 + gs, Bs + (tid + 256) * 16);
        __syncthreads();

        i32x4 af[4], bf[4];
#pragma unroll
        for (int m = 0; m < 4; ++m)
            af[m] = *(const i32x4*)&As[(wm * 64 + m * 16 + fr) * 64 + ((fg ^ w4) << 4)];
#pragma unroll
        for (int n = 0; n < 4; ++n)
            bf[n] = *(const i32x4*)&Bs[(wn * 64 + n * 16 + fr) * 64 + ((fg ^ w4) << 4)];
        __builtin_amdgcn_s_setprio(1);
#pragma unroll
        for (int m = 0; m < 4; ++m)
#pragma unroll
            for (int n = 0; n < 4; ++n)
                acc[m][n] = __builtin_amdgcn_mfma_i32_16x16x64_i8(af[m], bf[n], acc[m][n], 0, 0, 0);
        __builtin_amdgcn_s_setprio(0);
    }

    // epilogue: row = tm*128 + wm*64 + m*16 + fg*4 + r ; col = tn*128 + wn*64 + n*16 + fr
#pragma unroll
    for (int m = 0; m < 4; ++m) {
#pragma unroll
        for (int r = 0; r < 4; ++r) {
            const int grow = tm * 128 + wm * 64 + m * 16 + fg * 4 + r;
            const float rs = rowscale[grow];
#pragma unroll
            for (int n = 0; n < 4; ++n) {
                const int gcol = tn * 128 + wn * 64 + n * 16 + fr;
                const float v = (float)acc[m][n][r] * (rs * colscale[gcol]) + bias[gcol];
                if (epilogue == 0) {
                    const int b = grow >> 10, s = grow & 1023;
                    if (gcol < E_) {
                        const float vq = v * QSCL;          // fold softmax scale into q
                        const __half vh = (__half)vq;
                        const __half vl = (__half)(vq - (float)vh);
                        const int h = gcol >> 6, d = gcol & 63;
                        const size_t idx = (((size_t)(b * H_ + h) << 10) + s) * 64 + d;
                        qh_out[idx] = vh; ql_out[idx] = vl;
                    } else if (gcol < 2 * E_) {
                        const __half vh = (__half)v;
                        const __half vl = (__half)(v - (float)vh);
                        const int o = gcol - E_, h = o >> 6, d = o & 63;
                        const size_t idx = (((size_t)(b * H_ + h) << 10) + s) * 64 + d;
                        kh_out[idx] = vh; kl_out[idx] = vl;
                    } else {
                        const int o = gcol - 2 * E_, h = o >> 6, d = o & 63;
                        vt_out[(((size_t)(b * H_ + h) * 64 + d) << 10) + s] = (__half)v;
                    }
                } else {
                    out[(size_t)grow * E_ + gcol] = v;
                }
            }
        }
    }
}

// ---------------- flash attention: 8 waves / 128 q-rows per block ---------------------
// grid: 1280 blocks (XCD-clustered); LDS K dbuf shared by 8 waves -> 24 waves/CU.
__global__ __launch_bounds__(512) void attn_kernel(
    const __half* __restrict__ Qh, const __half* __restrict__ Ql,
    const __half* __restrict__ Kh, const __half* __restrict__ Kl,
    const __half* __restrict__ VT, __half* __restrict__ attn)
{
    __shared__ __half KhL[2][64 * 64];   // [buf][row*64 + col], XOR-swizzled 16B slots
    __shared__ __half KlL[2][64 * 64];
    __shared__ __half Pl[8][16 * 72];    // per-wave P bounce, stride 144B

    const int tid = threadIdx.x, lane = tid & 63, wave = tid >> 6;
    // XCD-clustered bijective remap: xcd = L&7 gets 20 contiguous heads
    const int L = blockIdx.x;
    const int sIdx = L >> 3;             // [0,160)
    const int bh = (L & 7) * 20 + (sIdx >> 3);
    const int qt = sIdx & 7;             // 8 q-tiles of 128 rows
    const int b = bh / H_, h = bh % H_;
    const int q0 = qt * 128 + wave * 16;
    const size_t base_sd = (size_t)bh * S_ * D_;
    const size_t base_ds = (size_t)bh * D_ * S_;
    const int fr = lane & 15, fg = lane >> 4;

    f16x8 qh0 = *(const f16x8*)&Qh[base_sd + (size_t)(q0 + fr) * 64 +      fg * 8];
    f16x8 qh1 = *(const f16x8*)&Qh[base_sd + (size_t)(q0 + fr) * 64 + 32 + fg * 8];
    f16x8 ql0 = *(const f16x8*)&Ql[base_sd + (size_t)(q0 + fr) * 64 +      fg * 8];
    f16x8 ql1 = *(const f16x8*)&Ql[base_sd + (size_t)(q0 + fr) * 64 + 32 + fg * 8];

    f32x4 o[4] = {};
    float mrow = -INFINITY, lrow = 0.f;   // per-lane: ONE q-row (q0 + fr)

    // stage 64x64 K chunk: 512 threads x 16B = 8KB per array; linear LDS dest,
    // inverse-swizzled global source (rule 21)
#define STAGEK(bf, kt) do {                                                   \
    const int row_ = tid >> 3;                                                \
    const int scb_ = ((tid & 7) * 16) ^ ((row_ & 7) << 4);                    \
    gload_lds16((const char*)(Kh + base_sd) + (size_t)((kt) + row_) * 128 + scb_, \
                (char*)&KhL[bf][0] + tid * 16);                               \
    gload_lds16((const char*)(Kl + base_sd) + (size_t)((kt) + row_) * 128 + scb_, \
                (char*)&KlL[bf][0] + tid * 16);                               \
} while (0)

    STAGEK(0, 0);
    __syncthreads();

    for (int it = 0; it < 16; ++it) {
        const int kt = it * 64;
        const int bf = it & 1;

        // VT loads early (global), consumed by PV at phase end -> latency hidden
        f16x8 vf[4][2];
#pragma unroll
        for (int dc = 0; dc < 4; ++dc) {
            const size_t vb = base_ds + (size_t)(dc * 16 + fr) * S_ + kt + fg * 8;
            vf[dc][0] = *(const f16x8*)&VT[vb];
            vf[dc][1] = *(const f16x8*)&VT[vb + 32];
        }
        if (it < 15) STAGEK(bf ^ 1, kt + 64);

        // swapped QK^T: st[t] = S^T tile; lane: q = q0+fr, k = kt + t*16 + fg*4 + r
        f32x4 st[4] = {};
        __builtin_amdgcn_s_setprio(1);
#pragma unroll
        for (int t = 0; t < 4; ++t) {
            const int rowb = (t * 16 + fr) * 128;
            const int c0 = (fg * 16)      ^ ((fr & 7) << 4);
            const int c1 = (64 + fg * 16) ^ ((fr & 7) << 4);
            f16x8 a0 = *(const f16x8*)((const char*)&KhL[bf][0] + rowb + c0);
            f16x8 a1 = *(const f16x8*)((const char*)&KhL[bf][0] + rowb + c1);
            f16x8 e0 = *(const f16x8*)((const char*)&KlL[bf][0] + rowb + c0);
            f16x8 e1 = *(const f16x8*)((const char*)&KlL[bf][0] + rowb + c1);
            st[t] = __builtin_amdgcn_mfma_f32_16x16x32_f16(a0, qh0, st[t], 0, 0, 0);
            st[t] = __builtin_amdgcn_mfma_f32_16x16x32_f16(a1, qh1, st[t], 0, 0, 0);
            st[t] = __builtin_amdgcn_mfma_f32_16x16x32_f16(a0, ql0, st[t], 0, 0, 0);
            st[t] = __builtin_amdgcn_mfma_f32_16x16x32_f16(a1, ql1, st[t], 0, 0, 0);
            st[t] = __builtin_amdgcn_mfma_f32_16x16x32_f16(e0, qh0, st[t], 0, 0, 0);
            st[t] = __builtin_amdgcn_mfma_f32_16x16x32_f16(e1, qh1, st[t], 0, 0, 0);
        }
        __builtin_amdgcn_s_setprio(0);

        // softmax over 64 kv: in-lane 16 + xor16 + xor32
        float mt0 = fmaxf(fmaxf(st[0][0], st[0][1]), fmaxf(st[0][2], st[0][3]));
        float mt1 = fmaxf(fmaxf(st[1][0], st[1][1]), fmaxf(st[1][2], st[1][3]));
        float mt2 = fmaxf(fmaxf(st[2][0], st[2][1]), fmaxf(st[2][2], st[2][3]));
        float mt3 = fmaxf(fmaxf(st[3][0], st[3][1]), fmaxf(st[3][2], st[3][3]));
        float mx = fmaxf(fmaxf(mt0, mt1), fmaxf(mt2, mt3));
        mx = fmaxf(mx, __shfl_xor(mx, 16));
        mx = fmaxf(mx, __shfl_xor(mx, 32));

        // defer-max (T13): skip o-rescale unless some row grew by > 8 (exp2 domain)
        if (!__all(mx - mrow <= 8.f)) {
            const float mn = fmaxf(mrow, mx);
            const float fsc = EXP2F(mrow - mn);   // exp2(-inf)=0 on first tile
            mrow = mn;
            lrow *= fsc;
            float fscr[4];
#pragma unroll
            for (int r = 0; r < 4; ++r) fscr[r] = __shfl(fsc, ((lane >> 4) << 2) + r);
#pragma unroll
            for (int dc = 0; dc < 4; ++dc)
#pragma unroll
                for (int r = 0; r < 4; ++r) o[dc][r] *= fscr[r];
        }

        float p[4][4];
        float rsum = 0.f;
#pragma unroll
        for (int t = 0; t < 4; ++t) {
            p[t][0] = EXP2F(st[t][0] - mrow);
            p[t][1] = EXP2F(st[t][1] - mrow);
            p[t][2] = EXP2F(st[t][2] - mrow);
            p[t][3] = EXP2F(st[t][3] - mrow);
            rsum += (p[t][0] + p[t][1]) + (p[t][2] + p[t][3]);
        }
        rsum += __shfl_xor(rsum, 16);
        rsum += __shfl_xor(rsum, 32);
        lrow += rsum;

        // P -> LDS bounce (transpose to A-frag layout)
#pragma unroll
        for (int t = 0; t < 4; ++t) {
            f16x4 pk;
            pk[0] = (_Float16)p[t][0]; pk[1] = (_Float16)p[t][1];
            pk[2] = (_Float16)p[t][2]; pk[3] = (_Float16)p[t][3];
            *(f16x4*)((char*)&Pl[wave][0] + fr * 144 + t * 32 + fg * 8) = pk;
        }
        asm volatile("s_waitcnt lgkmcnt(0)" ::: "memory");
        __builtin_amdgcn_sched_barrier(0);
        f16x8 pf0 = *(const f16x8*)((const char*)&Pl[wave][0] + fr * 144 +      fg * 16);
        f16x8 pf1 = *(const f16x8*)((const char*)&Pl[wave][0] + fr * 144 + 64 + fg * 16);
        __builtin_amdgcn_s_setprio(1);
#pragma unroll
        for (int dc = 0; dc < 4; ++dc) {
            o[dc] = __builtin_amdgcn_mfma_f32_16x16x32_f16(pf0, vf[dc][0], o[dc], 0, 0, 0);
            o[dc] = __builtin_amdgcn_mfma_f32_16x16x32_f16(pf1, vf[dc][1], o[dc], 0, 0, 0);
        }
        __builtin_amdgcn_s_setprio(0);
        __syncthreads();
    }

    float lrowr[4];
#pragma unroll
    for (int r = 0; r < 4; ++r) lrowr[r] = __shfl(lrow, ((lane >> 4) << 2) + r);
#pragma unroll
    for (int dc = 0; dc < 4; ++dc)
#pragma unroll
        for (int r = 0; r < 4; ++r) {
            const int t = (b << 10) + q0 + fg * 4 + r;
            attn[(size_t)t * E_ + h * 64 + dc * 16 + fr] = (__half)(o[dc][r] / lrowr[r]);
        }
#undef STAGEK
}

// ---------------- per-token symmetric int8 requant (int8 output for i8 GEMM) ---------
__global__ __launch_bounds__(256) void requant_kernel(
    const __half* __restrict__ attn, signed char* __restrict__ aq, float* __restrict__ as_)
{
    const int t = blockIdx.x;
    const int tid = threadIdx.x;
    __shared__ float red[4];
    const __half* row = attn + (size_t)t * E_;
    float x[5];
    float amax = 0.f;
#pragma unroll
    for (int j = 0; j < 5; ++j) {
        x[j] = (float)row[tid + j * 256];
        amax = fmaxf(amax, fabsf(x[j]));
    }
#pragma unroll
    for (int off = 1; off < 64; off <<= 1) amax = fmaxf(amax, __shfl_xor(amax, off));
    if ((tid & 63) == 0) red[tid >> 6] = amax;
    __syncthreads();
    amax = fmaxf(fmaxf(red[0], red[1]), fmaxf(red[2], red[3]));
    const float s = fmaxf(amax / 127.f, 1e-8f);
    if (tid == 0) as_[t] = s;
#pragma unroll
    for (int j = 0; j < 5; ++j) {
        float qv = fminf(fmaxf(rintf(x[j] / s), -127.f), 127.f);
        aq[(size_t)t * E_ + tid + j * 256] = (signed char)(int)qv;
    }
}

// ---------------- launch ----------------
extern "C" void kernel_launch(void* const* d_in, const int* in_sizes, int n_in,
                              void* d_out, int out_size, void* d_ws, size_t ws_size,
                              hipStream_t stream) {
    const int*   x_q         = (const int*)d_in[0];
    const float* in_scale    = (const float*)d_in[1];
    const int*   w_qkv       = (const int*)d_in[2];
    const float* w_qkv_scale = (const float*)d_in[3];
    const float* b_qkv       = (const float*)d_in[4];
    const int*   w_out       = (const int*)d_in[5];
    const float* w_out_scale = (const float*)d_in[6];
    const float* b_out       = (const float*)d_in[7];
    float* out = (float*)d_out;

    char* ws = (char*)d_ws;
    signed char* x_i8  = (signed char*)(ws);                 // 10,485,760 (dead after GEMM1)
    signed char* wq_i8 = (signed char*)(ws + 10485760);      //  4,915,200 (dead after GEMM1)
    __half* attn_f     = (__half*)(ws);                      // 20,971,520 (overlays x+wq)
    signed char* wo_i8 = (signed char*)(ws + 20971520);      //  1,638,400 (live till GEMM2)
    float*  a_s        = (float*)(ws + 22609920);            //     32,768
    __half* qh_f       = (__half*)(ws + 22642688);           // 20,971,520 [B,H,S,D]
    __half* ql_f       = (__half*)(ws + 43614208);           // 20,971,520
    __half* kh_f       = (__half*)(ws + 64585728);           // 20,971,520
    __half* kl_f       = (__half*)(ws + 85557248);           // 20,971,520
    __half* vt_f       = (__half*)(ws + 106528768);          // 20,971,520 [B,H,D,S]
    signed char* aq_i8 = (signed char*)(ws + 22642688);      // 10,485,760 (overlays qh_f)

    cvt8_all_kernel<<<(NX4 + NQ4 + NO4 + 255) / 256, 256, 0, stream>>>(
        x_q, w_qkv, w_out, (int*)x_i8, (int*)wq_i8, (int*)wo_i8);

    gemm_i8_kernel<<<(T_ / 128) * (QKV_ / 128), 256, 0, stream>>>(
        x_i8, wq_i8, T_, QKV_, E_, in_scale, w_qkv_scale, b_qkv, 0,
        qh_f, ql_f, kh_f, kl_f, vt_f, nullptr);

    attn_kernel<<<B_ * H_ * (S_ / 128), 512, 0, stream>>>(qh_f, ql_f, kh_f, kl_f, vt_f, attn_f);

    requant_kernel<<<T_, 256, 0, stream>>>(attn_f, aq_i8, a_s);

    gemm_i8_kernel<<<(T_ / 128) * (E_ / 128), 256, 0, stream>>>(
        aq_i8, wo_i8, T_, E_, E_, a_s, w_out_scale, b_out, 1,
        nullptr, nullptr, nullptr, nullptr, nullptr, out);
}

// Round 10
// 254.477 us; speedup vs baseline: 1.7817x; 1.2592x over previous
//
#include <hip/hip_runtime.h>
#include <hip/hip_bf16.h>
#include <hip/hip_fp16.h>

typedef __attribute__((ext_vector_type(4))) float f32x4;
typedef __attribute__((ext_vector_type(16))) float f32x16;
typedef __attribute__((ext_vector_type(8))) _Float16 f16x8;
typedef __attribute__((ext_vector_type(2))) __fp16 hf16x2;
typedef __attribute__((ext_vector_type(4))) int i32x4;
typedef __attribute__((ext_vector_type(2))) unsigned int u32x2;

#define B_   8
#define S_   1024
#define H_   20
#define D_   64
#define E_   1280
#define QKV_ 3840
#define T_   8192

#define EXP2F(x) __builtin_amdgcn_exp2f(x)
#define QSCL 0.1803368801111204f   /* 0.125 * log2(e) */

__device__ __forceinline__ void gload_lds16(const void* g, void* l) {
    __builtin_amdgcn_global_load_lds((const __attribute__((address_space(1))) int*)g,
                                     (__attribute__((address_space(3))) int*)l, 16, 0, 0);
}

__device__ __forceinline__ f32x16 zero16() {
    f32x16 z;
#pragma unroll
    for (int i = 0; i < 16; ++i) z[i] = 0.f;
    return z;
}

union pk8 { unsigned int u[4]; f16x8 v; };

// ---------------- int32 -> int8 pack, 3 tensors in one launch ----------------
#define NX4 (T_ * E_ / 4)
#define NQ4 (QKV_ * E_ / 4)
#define NO4 (E_ * E_ / 4)
__global__ __launch_bounds__(256) void cvt8_all_kernel(
    const int* __restrict__ x, const int* __restrict__ wq, const int* __restrict__ wo,
    int* __restrict__ xo, int* __restrict__ wqo, int* __restrict__ woo) {
    int i = blockIdx.x * 256 + threadIdx.x;
    const int* src; int* dst; int idx;
    if (i < NX4)              { src = x;  dst = xo;  idx = i; }
    else if (i < NX4 + NQ4)   { src = wq; dst = wqo; idx = i - NX4; }
    else if (i < NX4+NQ4+NO4) { src = wo; dst = woo; idx = i - NX4 - NQ4; }
    else return;
    i32x4 v = ((const i32x4*)src)[idx];
    dst[idx] = (v[0] & 255) | ((v[1] & 255) << 8) | ((v[2] & 255) << 16) | (v[3] << 24);
}

// ---------------- i8 GEMM (unchanged from r7) ----------------------------------------
__global__ __launch_bounds__(256) void gemm_i8_kernel(
    const signed char* __restrict__ A, const signed char* __restrict__ Bw,
    int M, int N, int K,
    const float* __restrict__ rowscale, const float* __restrict__ colscale,
    const float* __restrict__ bias, int epilogue,
    __half* __restrict__ qh_out, __half* __restrict__ ql_out,
    __half* __restrict__ kh_out, __half* __restrict__ kl_out,
    __half* __restrict__ vt_out, float* __restrict__ out)
{
    __shared__ signed char As[128 * 64];
    __shared__ signed char Bs[128 * 64];

    const int tid  = threadIdx.x;
    const int lane = tid & 63;
    const int wave = tid >> 6;
    const int wm = wave >> 1, wn = wave & 1;
    const int nTn = N >> 7;
    const int nwg = (M >> 7) * nTn;
    const int swz = (blockIdx.x & 7) * (nwg >> 3) + (blockIdx.x >> 3);
    const int tm = swz / nTn, tn = swz % nTn;

    i32x4 acc[4][4] = {};

    const int rl = tid >> 2;
    const int gs = (((tid & 3) ^ ((rl >> 1) & 3)) << 4);
    const size_t abase = (size_t)(tm * 128) * K;
    const size_t bbase = (size_t)(tn * 128) * K;

    const int fr = lane & 15;
    const int fg = lane >> 4;
    const int w4 = (fr >> 1) & 3;

    for (int k0 = 0; k0 < K; k0 += 64) {
        __syncthreads();
        gload_lds16(A  + abase + (size_t)rl        * K + k0 + gs, As + tid * 16);
        gload_lds16(A  + abase + (size_t)(rl + 64) * K + k0 + gs, As + (tid + 256) * 16);
        gload_lds16(Bw + bbase + (size_t)rl        * K + k0 + gs, Bs + tid * 16);
        gload_lds16(Bw + bbase + (size_t)(rl + 64) * K + k0 + gs, Bs + (tid + 256) * 16);
        __syncthreads();

        i32x4 af[4], bf[4];
#pragma unroll
        for (int m = 0; m < 4; ++m)
            af[m] = *(const i32x4*)&As[(wm * 64 + m * 16 + fr) * 64 + ((fg ^ w4) << 4)];
#pragma unroll
        for (int n = 0; n < 4; ++n)
            bf[n] = *(const i32x4*)&Bs[(wn * 64 + n * 16 + fr) * 64 + ((fg ^ w4) << 4)];
        __builtin_amdgcn_s_setprio(1);
#pragma unroll
        for (int m = 0; m < 4; ++m)
#pragma unroll
            for (int n = 0; n < 4; ++n)
                acc[m][n] = __builtin_amdgcn_mfma_i32_16x16x64_i8(af[m], bf[n], acc[m][n], 0, 0, 0);
        __builtin_amdgcn_s_setprio(0);
    }

#pragma unroll
    for (int m = 0; m < 4; ++m) {
#pragma unroll
        for (int r = 0; r < 4; ++r) {
            const int grow = tm * 128 + wm * 64 + m * 16 + fg * 4 + r;
            const float rs = rowscale[grow];
#pragma unroll
            for (int n = 0; n < 4; ++n) {
                const int gcol = tn * 128 + wn * 64 + n * 16 + fr;
                const float v = (float)acc[m][n][r] * (rs * colscale[gcol]) + bias[gcol];
                if (epilogue == 0) {
                    const int b = grow >> 10, s = grow & 1023;
                    if (gcol < E_) {
                        const float vq = v * QSCL;
                        const __half vh = (__half)vq;
                        const __half vl = (__half)(vq - (float)vh);
                        const int h = gcol >> 6, d = gcol & 63;
                        const size_t idx = (((size_t)(b * H_ + h) << 10) + s) * 64 + d;
                        qh_out[idx] = vh; ql_out[idx] = vl;
                    } else if (gcol < 2 * E_) {
                        const __half vh = (__half)v;
                        const __half vl = (__half)(v - (float)vh);
                        const int o = gcol - E_, h = o >> 6, d = o & 63;
                        const size_t idx = (((size_t)(b * H_ + h) << 10) + s) * 64 + d;
                        kh_out[idx] = vh; kl_out[idx] = vl;
                    } else {
                        const int o = gcol - 2 * E_, h = o >> 6, d = o & 63;
                        vt_out[(((size_t)(b * H_ + h) * 64 + d) << 10) + s] = (__half)v;
                    }
                } else {
                    out[(size_t)grow * E_ + gcol] = v;
                }
            }
        }
    }
}

// ---------------- flash attention v3: 32x32 swapped QK, in-register softmax ----------
// 4 waves x 32 q-rows = 128 q/block; grid 1280 (XCD-clustered).
// st/o are S^T/O^T: col = lane&31 = q -> softmax & rescale lane-local (T12 pattern).
__global__ __launch_bounds__(256) void attn_kernel(
    const __half* __restrict__ Qh, const __half* __restrict__ Ql,
    const __half* __restrict__ Kh, const __half* __restrict__ Kl,
    const __half* __restrict__ VT, __half* __restrict__ attn)
{
    __shared__ char SM[32768];   // K dbuf: Kh[2][64][128B] @0, Kl[2][64][128B] @16384; O-bounce reuse
    const int tid = threadIdx.x, lane = tid & 63, wave = tid >> 6;
    const int L = blockIdx.x;
    const int sIdx = L >> 3;
    const int bh = (L & 7) * 20 + (sIdx >> 3);   // xcd-clustered heads
    const int qt = sIdx & 7;
    const int b = bh / H_, h = bh % H_;
    const int q0 = qt * 128 + wave * 32;
    const size_t base_sd = (size_t)bh * S_ * D_;
    const size_t base_ds = (size_t)bh * D_ * S_;
    const int qL = lane & 31, hi = lane >> 5;

#define KHbuf(bf) ((char*)SM + (bf) * 8192)
#define KLbuf(bf) ((char*)SM + 16384 + (bf) * 8192)

    // Q B-frags: B[d][q]: lane = q, d = s*16 + hi*8 + j
    f16x8 qhf[4], qlf[4];
#pragma unroll
    for (int s = 0; s < 4; ++s) {
        const size_t qa = base_sd + (size_t)(q0 + qL) * 64 + s * 16 + hi * 8;
        qhf[s] = *(const f16x8*)&Qh[qa];
        qlf[s] = *(const f16x8*)&Ql[qa];
    }

    f32x16 o0 = zero16(), o1 = zero16();
    float mrow = -INFINITY, lrow = 0.f;   // per-lane: ONE q-row (q0 + qL)

#define STAGEK(bf, kt) do {                                                   \
    _Pragma("unroll")                                                         \
    for (int c_ = 0; c_ < 2; ++c_) {                                          \
        const int qb_ = c_ * 4096 + tid * 16;                                 \
        const int row_ = qb_ >> 7, cb_ = qb_ & 127;                           \
        const int scb_ = cb_ ^ ((row_ & 7) << 4);                             \
        gload_lds16((const char*)(Kh + base_sd) + (size_t)((kt) + row_) * 128 + scb_, \
                    KHbuf(bf) + qb_);                                         \
        gload_lds16((const char*)(Kl + base_sd) + (size_t)((kt) + row_) * 128 + scb_, \
                    KLbuf(bf) + qb_);                                         \
    }                                                                         \
} while (0)

// QK on one 32-k tile: score^T = Kh*Qh + Kl*Qh + Kh*Ql
#define QKTILE(ST, KT2) do {                                                  \
    _Pragma("unroll")                                                         \
    for (int s_ = 0; s_ < 4; ++s_) {                                          \
        const int row_ = (KT2) * 32 + qL;                                     \
        const int off_ = row_ * 128 + ((s_ * 32 + hi * 16) ^ ((row_ & 7) << 4)); \
        f16x8 ah_ = *(const f16x8*)(KHbuf(bf) + off_);                        \
        f16x8 al_ = *(const f16x8*)(KLbuf(bf) + off_);                        \
        ST = __builtin_amdgcn_mfma_f32_32x32x16_f16(ah_, qhf[s_], ST, 0, 0, 0); \
        ST = __builtin_amdgcn_mfma_f32_32x32x16_f16(al_, qhf[s_], ST, 0, 0, 0); \
        ST = __builtin_amdgcn_mfma_f32_32x32x16_f16(ah_, qlf[s_], ST, 0, 0, 0); \
    }                                                                         \
} while (0)

// pack exp'd ST (16 f32) into two PV B-frags via cvt_pkrtz + permlane32_swap (T12)
#define PACKP(ST, BF0, BF1) do {                                              \
    unsigned pk_[8];                                                          \
    _Pragma("unroll")                                                         \
    for (int j_ = 0; j_ < 8; ++j_) {                                          \
        union { hf16x2 h; unsigned u; } cv_;                                  \
        cv_.h = __builtin_amdgcn_cvt_pkrtz(ST[2 * j_], ST[2 * j_ + 1]);       \
        pk_[j_] = cv_.u;                                                      \
    }                                                                         \
    u32x2 rA_ = __builtin_amdgcn_permlane32_swap(pk_[0], pk_[2], false, false); \
    u32x2 rB_ = __builtin_amdgcn_permlane32_swap(pk_[1], pk_[3], false, false); \
    BF0.u[0] = rA_[0]; BF0.u[1] = rB_[0]; BF0.u[2] = rA_[1]; BF0.u[3] = rB_[1]; \
    u32x2 rC_ = __builtin_amdgcn_permlane32_swap(pk_[4], pk_[6], false, false); \
    u32x2 rD_ = __builtin_amdgcn_permlane32_swap(pk_[5], pk_[7], false, false); \
    BF1.u[0] = rC_[0]; BF1.u[1] = rD_[0]; BF1.u[2] = rC_[1]; BF1.u[3] = rD_[1]; \
} while (0)

    STAGEK(0, 0);
    __syncthreads();

    for (int it = 0; it < 16; ++it) {
        const int kt = it * 64, bf = it & 1;
        if (it < 15) STAGEK(bf ^ 1, kt + 64);

        // V^T A-frags: A[d][k]: lane = d, k = ks*16 + hi*8 + j  (direct row-major loads)
        f16x8 vf0[4], vf1[4];
#pragma unroll
        for (int ks = 0; ks < 4; ++ks) {
            const size_t va = base_ds + (size_t)qL * S_ + kt + ks * 16 + hi * 8;
            vf0[ks] = *(const f16x8*)&VT[va];
            vf1[ks] = *(const f16x8*)&VT[va + (size_t)32 * S_];
        }

        f32x16 st0 = zero16(), st1 = zero16();
        __builtin_amdgcn_s_setprio(1);
        QKTILE(st0, 0);
        QKTILE(st1, 1);
        __builtin_amdgcn_s_setprio(0);

        // softmax: lane holds 32 of the 64 k for its q; partner (lane^32) the rest
        float mx = -INFINITY;
#pragma unroll
        for (int r = 0; r < 16; ++r) { mx = fmaxf(mx, st0[r]); mx = fmaxf(mx, st1[r]); }
        mx = fmaxf(mx, __shfl_xor(mx, 32));
        const float mn = fmaxf(mrow, mx);
        const float fsc = EXP2F(mrow - mn);   // exp2(-inf)=0 first tile
        mrow = mn;
        lrow *= fsc;
#pragma unroll
        for (int r = 0; r < 16; ++r) { o0[r] *= fsc; o1[r] *= fsc; }

        float rsum = 0.f;
#pragma unroll
        for (int r = 0; r < 16; ++r) { st0[r] = EXP2F(st0[r] - mn); rsum += st0[r]; }
#pragma unroll
        for (int r = 0; r < 16; ++r) { st1[r] = EXP2F(st1[r] - mn); rsum += st1[r]; }
        rsum += __shfl_xor(rsum, 32);
        lrow += rsum;

        // P -> f16 B-frags, fully in-register
        pk8 Bf0, Bf1, Bf2, Bf3;
        PACKP(st0, Bf0, Bf1);
        PACKP(st1, Bf2, Bf3);

        __builtin_amdgcn_s_setprio(1);
        o0 = __builtin_amdgcn_mfma_f32_32x32x16_f16(vf0[0], Bf0.v, o0, 0, 0, 0);
        o0 = __builtin_amdgcn_mfma_f32_32x32x16_f16(vf0[1], Bf1.v, o0, 0, 0, 0);
        o0 = __builtin_amdgcn_mfma_f32_32x32x16_f16(vf0[2], Bf2.v, o0, 0, 0, 0);
        o0 = __builtin_amdgcn_mfma_f32_32x32x16_f16(vf0[3], Bf3.v, o0, 0, 0, 0);
        o1 = __builtin_amdgcn_mfma_f32_32x32x16_f16(vf1[0], Bf0.v, o1, 0, 0, 0);
        o1 = __builtin_amdgcn_mfma_f32_32x32x16_f16(vf1[1], Bf1.v, o1, 0, 0, 0);
        o1 = __builtin_amdgcn_mfma_f32_32x32x16_f16(vf1[2], Bf2.v, o1, 0, 0, 0);
        o1 = __builtin_amdgcn_mfma_f32_32x32x16_f16(vf1[3], Bf3.v, o1, 0, 0, 0);
        __builtin_amdgcn_s_setprio(0);

        __syncthreads();
    }

    // epilogue: O^T -> LDS transpose (per-wave region over dead K LDS) -> coalesced f16
    const float inv = 1.f / lrow;
    float* ob = (float*)((char*)SM + wave * 4224);   // [32][33] f32
#pragma unroll
    for (int dt = 0; dt < 2; ++dt) {
#pragma unroll
        for (int r = 0; r < 16; ++r) {
            const int dl = (r & 3) + 8 * (r >> 2) + 4 * hi;
            ob[qL * 33 + dl] = (dt ? o1[r] : o0[r]) * inv;
        }
        asm volatile("s_waitcnt lgkmcnt(0)" ::: "memory");
        __builtin_amdgcn_sched_barrier(0);
        f16x8 w0, w1;
#pragma unroll
        for (int j = 0; j < 8; ++j) {
            w0[j] = (_Float16)ob[qL * 33 + hi * 16 + j];
            w1[j] = (_Float16)ob[qL * 33 + hi * 16 + 8 + j];
        }
        __half* dst = attn + (size_t)((b << 10) + q0 + qL) * E_ + h * 64 + dt * 32 + hi * 16;
        *(f16x8*)dst = w0;
        *(f16x8*)(dst + 8) = w1;
        asm volatile("s_waitcnt lgkmcnt(0)" ::: "memory");
        __builtin_amdgcn_sched_barrier(0);
    }
#undef STAGEK
#undef QKTILE
#undef PACKP
#undef KHbuf
#undef KLbuf
}

// ---------------- per-token symmetric int8 requant (int8 output for i8 GEMM) ---------
__global__ __launch_bounds__(256) void requant_kernel(
    const __half* __restrict__ attn, signed char* __restrict__ aq, float* __restrict__ as_)
{
    const int t = blockIdx.x;
    const int tid = threadIdx.x;
    __shared__ float red[4];
    const __half* row = attn + (size_t)t * E_;
    float x[5];
    float amax = 0.f;
#pragma unroll
    for (int j = 0; j < 5; ++j) {
        x[j] = (float)row[tid + j * 256];
        amax = fmaxf(amax, fabsf(x[j]));
    }
#pragma unroll
    for (int off = 1; off < 64; off <<= 1) amax = fmaxf(amax, __shfl_xor(amax, off));
    if ((tid & 63) == 0) red[tid >> 6] = amax;
    __syncthreads();
    amax = fmaxf(fmaxf(red[0], red[1]), fmaxf(red[2], red[3]));
    const float s = fmaxf(amax / 127.f, 1e-8f);
    if (tid == 0) as_[t] = s;
#pragma unroll
    for (int j = 0; j < 5; ++j) {
        float qv = fminf(fmaxf(rintf(x[j] / s), -127.f), 127.f);
        aq[(size_t)t * E_ + tid + j * 256] = (signed char)(int)qv;
    }
}

// ---------------- launch ----------------
extern "C" void kernel_launch(void* const* d_in, const int* in_sizes, int n_in,
                              void* d_out, int out_size, void* d_ws, size_t ws_size,
                              hipStream_t stream) {
    const int*   x_q         = (const int*)d_in[0];
    const float* in_scale    = (const float*)d_in[1];
    const int*   w_qkv       = (const int*)d_in[2];
    const float* w_qkv_scale = (const float*)d_in[3];
    const float* b_qkv       = (const float*)d_in[4];
    const int*   w_out       = (const int*)d_in[5];
    const float* w_out_scale = (const float*)d_in[6];
    const float* b_out       = (const float*)d_in[7];
    float* out = (float*)d_out;

    char* ws = (char*)d_ws;
    signed char* x_i8  = (signed char*)(ws);                 // 10,485,760 (dead after GEMM1)
    signed char* wq_i8 = (signed char*)(ws + 10485760);      //  4,915,200 (dead after GEMM1)
    __half* attn_f     = (__half*)(ws);                      // 20,971,520 (overlays x+wq)
    signed char* wo_i8 = (signed char*)(ws + 20971520);      //  1,638,400 (live till GEMM2)
    float*  a_s        = (float*)(ws + 22609920);            //     32,768
    __half* qh_f       = (__half*)(ws + 22642688);           // 20,971,520 [B,H,S,D]
    __half* ql_f       = (__half*)(ws + 43614208);           // 20,971,520
    __half* kh_f       = (__half*)(ws + 64585728);           // 20,971,520
    __half* kl_f       = (__half*)(ws + 85557248);           // 20,971,520
    __half* vt_f       = (__half*)(ws + 106528768);          // 20,971,520 [B,H,D,S]
    signed char* aq_i8 = (signed char*)(ws + 22642688);      // 10,485,760 (overlays qh_f)

    cvt8_all_kernel<<<(NX4 + NQ4 + NO4 + 255) / 256, 256, 0, stream>>>(
        x_q, w_qkv, w_out, (int*)x_i8, (int*)wq_i8, (int*)wo_i8);

    gemm_i8_kernel<<<(T_ / 128) * (QKV_ / 128), 256, 0, stream>>>(
        x_i8, wq_i8, T_, QKV_, E_, in_scale, w_qkv_scale, b_qkv, 0,
        qh_f, ql_f, kh_f, kl_f, vt_f, nullptr);

    attn_kernel<<<B_ * H_ * (S_ / 128), 256, 0, stream>>>(qh_f, ql_f, kh_f, kl_f, vt_f, attn_f);

    requant_kernel<<<T_, 256, 0, stream>>>(attn_f, aq_i8, a_s);

    gemm_i8_kernel<<<(T_ / 128) * (E_ / 128), 256, 0, stream>>>(
        aq_i8, wo_i8, T_, E_, E_, a_s, w_out_scale, b_out, 1,
        nullptr, nullptr, nullptr, nullptr, nullptr, out);
}

// Round 11
// 250.743 us; speedup vs baseline: 1.8083x; 1.0149x over previous
//
#include <hip/hip_runtime.h>
#include <hip/hip_bf16.h>
#include <hip/hip_fp16.h>

typedef __attribute__((ext_vector_type(4))) float f32x4;
typedef __attribute__((ext_vector_type(16))) float f32x16;
typedef __attribute__((ext_vector_type(8))) _Float16 f16x8;
typedef __attribute__((ext_vector_type(2))) __fp16 hf16x2;
typedef __attribute__((ext_vector_type(4))) int i32x4;
typedef __attribute__((ext_vector_type(2))) unsigned int u32x2;

#define B_   8
#define S_   1024
#define H_   20
#define D_   64
#define E_   1280
#define QKV_ 3840
#define T_   8192

#define EXP2F(x) __builtin_amdgcn_exp2f(x)
#define QSCL 0.1803368801111204f   /* 0.125 * log2(e) */

__device__ __forceinline__ void gload_lds16(const void* g, void* l) {
    __builtin_amdgcn_global_load_lds((const __attribute__((address_space(1))) int*)g,
                                     (__attribute__((address_space(3))) int*)l, 16, 0, 0);
}

__device__ __forceinline__ f32x16 zero16() {
    f32x16 z;
#pragma unroll
    for (int i = 0; i < 16; ++i) z[i] = 0.f;
    return z;
}

union pk8 { unsigned int u[4]; f16x8 v; };

// ---------------- int32 -> int8 pack, 3 tensors in one launch ----------------
#define NX4 (T_ * E_ / 4)
#define NQ4 (QKV_ * E_ / 4)
#define NO4 (E_ * E_ / 4)
__global__ __launch_bounds__(256) void cvt8_all_kernel(
    const int* __restrict__ x, const int* __restrict__ wq, const int* __restrict__ wo,
    int* __restrict__ xo, int* __restrict__ wqo, int* __restrict__ woo) {
    int i = blockIdx.x * 256 + threadIdx.x;
    const int* src; int* dst; int idx;
    if (i < NX4)              { src = x;  dst = xo;  idx = i; }
    else if (i < NX4 + NQ4)   { src = wq; dst = wqo; idx = i - NX4; }
    else if (i < NX4+NQ4+NO4) { src = wo; dst = woo; idx = i - NX4 - NQ4; }
    else return;
    i32x4 v = ((const i32x4*)src)[idx];
    dst[idx] = (v[0] & 255) | ((v[1] & 255) << 8) | ((v[2] & 255) << 16) | (v[3] << 24);
}

// ---------------- i8 GEMM: C[M,N] = A[M,K] * B[N,K]^T (i32 accum, exact) -------------
// 128x128 tile, BK=128, global_load_lds w16, 8-slot XOR swizzle, fused dequant epi.
__global__ __launch_bounds__(256) void gemm_i8_kernel(
    const signed char* __restrict__ A, const signed char* __restrict__ Bw,
    int M, int N, int K,
    const float* __restrict__ rowscale, const float* __restrict__ colscale,
    const float* __restrict__ bias, int epilogue,
    __half* __restrict__ qh_out, __half* __restrict__ ql_out,
    __half* __restrict__ kh_out, __half* __restrict__ kl_out,
    __half* __restrict__ vt_out, float* __restrict__ out)
{
    __shared__ signed char As[128 * 128];
    __shared__ signed char Bs[128 * 128];

    const int tid  = threadIdx.x;
    const int lane = tid & 63;
    const int wave = tid >> 6;
    const int wm = wave >> 1, wn = wave & 1;
    const int nTn = N >> 7;
    const int nwg = (M >> 7) * nTn;                   // multiple of 8 for our shapes
    const int swz = (blockIdx.x & 7) * (nwg >> 3) + (blockIdx.x >> 3);
    const int tm = swz / nTn, tn = swz % nTn;

    i32x4 acc[4][4] = {};

    const size_t abase = (size_t)(tm * 128) * K;
    const size_t bbase = (size_t)(tn * 128) * K;

    const int fr = lane & 15;
    const int fg = lane >> 4;

    for (int k0 = 0; k0 < K; k0 += 128) {
        __syncthreads();
#pragma unroll
        for (int c = 0; c < 4; ++c) {
            const int t16 = c * 256 + tid;
            const int row = t16 >> 3;
            const int gsl = ((t16 & 7) ^ (row & 7)) << 4;   // inverse-swizzled global slot
            gload_lds16(A  + abase + (size_t)row * K + k0 + gsl, As + t16 * 16);
            gload_lds16(Bw + bbase + (size_t)row * K + k0 + gsl, Bs + t16 * 16);
        }
        __syncthreads();

#pragma unroll
        for (int kk = 0; kk < 2; ++kk) {
            i32x4 af[4], bf[4];
#pragma unroll
            for (int m = 0; m < 4; ++m)
                af[m] = *(const i32x4*)&As[(wm * 64 + m * 16 + fr) * 128 +
                                           ((((kk << 2) | fg) ^ (fr & 7)) << 4)];
#pragma unroll
            for (int n = 0; n < 4; ++n)
                bf[n] = *(const i32x4*)&Bs[(wn * 64 + n * 16 + fr) * 128 +
                                           ((((kk << 2) | fg) ^ (fr & 7)) << 4)];
            __builtin_amdgcn_s_setprio(1);
#pragma unroll
            for (int m = 0; m < 4; ++m)
#pragma unroll
                for (int n = 0; n < 4; ++n)
                    acc[m][n] = __builtin_amdgcn_mfma_i32_16x16x64_i8(af[m], bf[n], acc[m][n], 0, 0, 0);
            __builtin_amdgcn_s_setprio(0);
        }
    }

    // epilogue: row = tm*128 + wm*64 + m*16 + fg*4 + r ; col = tn*128 + wn*64 + n*16 + fr
#pragma unroll
    for (int m = 0; m < 4; ++m) {
#pragma unroll
        for (int r = 0; r < 4; ++r) {
            const int grow = tm * 128 + wm * 64 + m * 16 + fg * 4 + r;
            const float rs = rowscale[grow];
#pragma unroll
            for (int n = 0; n < 4; ++n) {
                const int gcol = tn * 128 + wn * 64 + n * 16 + fr;
                const float v = (float)acc[m][n][r] * (rs * colscale[gcol]) + bias[gcol];
                if (epilogue == 0) {
                    const int b = grow >> 10, s = grow & 1023;
                    if (gcol < E_) {
                        const float vq = v * QSCL;
                        const __half vh = (__half)vq;
                        const __half vl = (__half)(vq - (float)vh);
                        const int h = gcol >> 6, d = gcol & 63;
                        const size_t idx = (((size_t)(b * H_ + h) << 10) + s) * 64 + d;
                        qh_out[idx] = vh; ql_out[idx] = vl;
                    } else if (gcol < 2 * E_) {
                        const __half vh = (__half)v;
                        const __half vl = (__half)(v - (float)vh);
                        const int o = gcol - E_, h = o >> 6, d = o & 63;
                        const size_t idx = (((size_t)(b * H_ + h) << 10) + s) * 64 + d;
                        kh_out[idx] = vh; kl_out[idx] = vl;
                    } else {
                        const int o = gcol - 2 * E_, h = o >> 6, d = o & 63;
                        vt_out[(((size_t)(b * H_ + h) * 64 + d) << 10) + s] = (__half)v;
                    }
                } else {
                    out[(size_t)grow * E_ + gcol] = v;
                }
            }
        }
    }
}

// ---------------- flash attention v3 + defer-max: 32x32 swapped QK ----------
// 4 waves x 32 q-rows = 128 q/block; grid 1280 (XCD-clustered).
// st/o are S^T/O^T: col = lane&31 = q -> softmax & rescale lane-local (T12 pattern).
__global__ __launch_bounds__(256) void attn_kernel(
    const __half* __restrict__ Qh, const __half* __restrict__ Ql,
    const __half* __restrict__ Kh, const __half* __restrict__ Kl,
    const __half* __restrict__ VT, __half* __restrict__ attn)
{
    __shared__ char SM[32768];   // K dbuf: Kh[2][64][128B] @0, Kl[2][64][128B] @16384
    const int tid = threadIdx.x, lane = tid & 63, wave = tid >> 6;
    const int L = blockIdx.x;
    const int sIdx = L >> 3;
    const int bh = (L & 7) * 20 + (sIdx >> 3);   // xcd-clustered heads
    const int qt = sIdx & 7;
    const int b = bh / H_, h = bh % H_;
    const int q0 = qt * 128 + wave * 32;
    const size_t base_sd = (size_t)bh * S_ * D_;
    const size_t base_ds = (size_t)bh * D_ * S_;
    const int qL = lane & 31, hi = lane >> 5;

#define KHbuf(bf) ((char*)SM + (bf) * 8192)
#define KLbuf(bf) ((char*)SM + 16384 + (bf) * 8192)

    // Q B-frags: B[d][q]: lane = q, d = s*16 + hi*8 + j
    f16x8 qhf[4], qlf[4];
#pragma unroll
    for (int s = 0; s < 4; ++s) {
        const size_t qa = base_sd + (size_t)(q0 + qL) * 64 + s * 16 + hi * 8;
        qhf[s] = *(const f16x8*)&Qh[qa];
        qlf[s] = *(const f16x8*)&Ql[qa];
    }

    f32x16 o0 = zero16(), o1 = zero16();
    float mrow = -INFINITY, lrow = 0.f;   // per-lane: ONE q-row (q0 + qL)

#define STAGEK(bf, kt) do {                                                   \
    _Pragma("unroll")                                                         \
    for (int c_ = 0; c_ < 2; ++c_) {                                          \
        const int qb_ = c_ * 4096 + tid * 16;                                 \
        const int row_ = qb_ >> 7, cb_ = qb_ & 127;                           \
        const int scb_ = cb_ ^ ((row_ & 7) << 4);                             \
        gload_lds16((const char*)(Kh + base_sd) + (size_t)((kt) + row_) * 128 + scb_, \
                    KHbuf(bf) + qb_);                                         \
        gload_lds16((const char*)(Kl + base_sd) + (size_t)((kt) + row_) * 128 + scb_, \
                    KLbuf(bf) + qb_);                                         \
    }                                                                         \
} while (0)

// QK on one 32-k tile: score^T = Kh*Qh + Kl*Qh + Kh*Ql
#define QKTILE(ST, KT2) do {                                                  \
    _Pragma("unroll")                                                         \
    for (int s_ = 0; s_ < 4; ++s_) {                                          \
        const int row_ = (KT2) * 32 + qL;                                     \
        const int off_ = row_ * 128 + ((s_ * 32 + hi * 16) ^ ((row_ & 7) << 4)); \
        f16x8 ah_ = *(const f16x8*)(KHbuf(bf) + off_);                        \
        f16x8 al_ = *(const f16x8*)(KLbuf(bf) + off_);                        \
        ST = __builtin_amdgcn_mfma_f32_32x32x16_f16(ah_, qhf[s_], ST, 0, 0, 0); \
        ST = __builtin_amdgcn_mfma_f32_32x32x16_f16(al_, qhf[s_], ST, 0, 0, 0); \
        ST = __builtin_amdgcn_mfma_f32_32x32x16_f16(ah_, qlf[s_], ST, 0, 0, 0); \
    }                                                                         \
} while (0)

// pack exp'd ST (16 f32) into two PV B-frags via cvt_pkrtz + permlane32_swap (T12)
#define PACKP(ST, BF0, BF1) do {                                              \
    unsigned pk_[8];                                                          \
    _Pragma("unroll")                                                         \
    for (int j_ = 0; j_ < 8; ++j_) {                                          \
        union { hf16x2 h; unsigned u; } cv_;                                  \
        cv_.h = __builtin_amdgcn_cvt_pkrtz(ST[2 * j_], ST[2 * j_ + 1]);       \
        pk_[j_] = cv_.u;                                                      \
    }                                                                         \
    u32x2 rA_ = __builtin_amdgcn_permlane32_swap(pk_[0], pk_[2], false, false); \
    u32x2 rB_ = __builtin_amdgcn_permlane32_swap(pk_[1], pk_[3], false, false); \
    BF0.u[0] = rA_[0]; BF0.u[1] = rB_[0]; BF0.u[2] = rA_[1]; BF0.u[3] = rB_[1]; \
    u32x2 rC_ = __builtin_amdgcn_permlane32_swap(pk_[4], pk_[6], false, false); \
    u32x2 rD_ = __builtin_amdgcn_permlane32_swap(pk_[5], pk_[7], false, false); \
    BF1.u[0] = rC_[0]; BF1.u[1] = rD_[0]; BF1.u[2] = rC_[1]; BF1.u[3] = rD_[1]; \
} while (0)

    STAGEK(0, 0);
    __syncthreads();

    for (int it = 0; it < 16; ++it) {
        const int kt = it * 64, bf = it & 1;
        if (it < 15) STAGEK(bf ^ 1, kt + 64);

        // V^T A-frags: A[d][k]: lane = d, k = ks*16 + hi*8 + j  (direct row-major loads)
        f16x8 vf0[4], vf1[4];
#pragma unroll
        for (int ks = 0; ks < 4; ++ks) {
            const size_t va = base_ds + (size_t)qL * S_ + kt + ks * 16 + hi * 8;
            vf0[ks] = *(const f16x8*)&VT[va];
            vf1[ks] = *(const f16x8*)&VT[va + (size_t)32 * S_];
        }

        f32x16 st0 = zero16(), st1 = zero16();
        __builtin_amdgcn_s_setprio(1);
        QKTILE(st0, 0);
        QKTILE(st1, 1);
        __builtin_amdgcn_s_setprio(0);

        // softmax: lane holds 32 of the 64 k for its q; partner (lane^32) the rest
        float mx = -INFINITY;
#pragma unroll
        for (int r = 0; r < 16; ++r) { mx = fmaxf(mx, st0[r]); mx = fmaxf(mx, st1[r]); }
        mx = fmaxf(mx, __shfl_xor(mx, 32));

        // defer-max (T13): skip o-rescale unless some row grew by > 8 (exp2 domain)
        if (!__all(mx - mrow <= 8.f)) {
            const float mn = fmaxf(mrow, mx);
            const float fsc = EXP2F(mrow - mn);   // exp2(-inf)=0 first tile
            mrow = mn;
            lrow *= fsc;
#pragma unroll
            for (int r = 0; r < 16; ++r) { o0[r] *= fsc; o1[r] *= fsc; }
        }

        float rsum = 0.f;
#pragma unroll
        for (int r = 0; r < 16; ++r) { st0[r] = EXP2F(st0[r] - mrow); rsum += st0[r]; }
#pragma unroll
        for (int r = 0; r < 16; ++r) { st1[r] = EXP2F(st1[r] - mrow); rsum += st1[r]; }
        rsum += __shfl_xor(rsum, 32);
        lrow += rsum;

        // P -> f16 B-frags, fully in-register
        pk8 Bf0, Bf1, Bf2, Bf3;
        PACKP(st0, Bf0, Bf1);
        PACKP(st1, Bf2, Bf3);

        __builtin_amdgcn_s_setprio(1);
        o0 = __builtin_amdgcn_mfma_f32_32x32x16_f16(vf0[0], Bf0.v, o0, 0, 0, 0);
        o0 = __builtin_amdgcn_mfma_f32_32x32x16_f16(vf0[1], Bf1.v, o0, 0, 0, 0);
        o0 = __builtin_amdgcn_mfma_f32_32x32x16_f16(vf0[2], Bf2.v, o0, 0, 0, 0);
        o0 = __builtin_amdgcn_mfma_f32_32x32x16_f16(vf0[3], Bf3.v, o0, 0, 0, 0);
        o1 = __builtin_amdgcn_mfma_f32_32x32x16_f16(vf1[0], Bf0.v, o1, 0, 0, 0);
        o1 = __builtin_amdgcn_mfma_f32_32x32x16_f16(vf1[1], Bf1.v, o1, 0, 0, 0);
        o1 = __builtin_amdgcn_mfma_f32_32x32x16_f16(vf1[2], Bf2.v, o1, 0, 0, 0);
        o1 = __builtin_amdgcn_mfma_f32_32x32x16_f16(vf1[3], Bf3.v, o1, 0, 0, 0);
        __builtin_amdgcn_s_setprio(0);

        __syncthreads();
    }

    // epilogue: O^T -> LDS transpose (per-wave region over dead K LDS) -> coalesced f16
    const float inv = 1.f / lrow;
    float* ob = (float*)((char*)SM + wave * 4224);   // [32][33] f32
#pragma unroll
    for (int dt = 0; dt < 2; ++dt) {
#pragma unroll
        for (int r = 0; r < 16; ++r) {
            const int dl = (r & 3) + 8 * (r >> 2) + 4 * hi;
            ob[qL * 33 + dl] = (dt ? o1[r] : o0[r]) * inv;
        }
        asm volatile("s_waitcnt lgkmcnt(0)" ::: "memory");
        __builtin_amdgcn_sched_barrier(0);
        f16x8 w0, w1;
#pragma unroll
        for (int j = 0; j < 8; ++j) {
            w0[j] = (_Float16)ob[qL * 33 + hi * 16 + j];
            w1[j] = (_Float16)ob[qL * 33 + hi * 16 + 8 + j];
        }
        __half* dst = attn + (size_t)((b << 10) + q0 + qL) * E_ + h * 64 + dt * 32 + hi * 16;
        *(f16x8*)dst = w0;
        *(f16x8*)(dst + 8) = w1;
        asm volatile("s_waitcnt lgkmcnt(0)" ::: "memory");
        __builtin_amdgcn_sched_barrier(0);
    }
#undef STAGEK
#undef QKTILE
#undef PACKP
#undef KHbuf
#undef KLbuf
}

// ---------------- per-token symmetric int8 requant (int8 output for i8 GEMM) ---------
__global__ __launch_bounds__(256) void requant_kernel(
    const __half* __restrict__ attn, signed char* __restrict__ aq, float* __restrict__ as_)
{
    const int t = blockIdx.x;
    const int tid = threadIdx.x;
    __shared__ float red[4];
    const __half* row = attn + (size_t)t * E_;
    float x[5];
    float amax = 0.f;
#pragma unroll
    for (int j = 0; j < 5; ++j) {
        x[j] = (float)row[tid + j * 256];
        amax = fmaxf(amax, fabsf(x[j]));
    }
#pragma unroll
    for (int off = 1; off < 64; off <<= 1) amax = fmaxf(amax, __shfl_xor(amax, off));
    if ((tid & 63) == 0) red[tid >> 6] = amax;
    __syncthreads();
    amax = fmaxf(fmaxf(red[0], red[1]), fmaxf(red[2], red[3]));
    const float s = fmaxf(amax / 127.f, 1e-8f);
    if (tid == 0) as_[t] = s;
#pragma unroll
    for (int j = 0; j < 5; ++j) {
        float qv = fminf(fmaxf(rintf(x[j] / s), -127.f), 127.f);
        aq[(size_t)t * E_ + tid + j * 256] = (signed char)(int)qv;
    }
}

// ---------------- launch ----------------
extern "C" void kernel_launch(void* const* d_in, const int* in_sizes, int n_in,
                              void* d_out, int out_size, void* d_ws, size_t ws_size,
                              hipStream_t stream) {
    const int*   x_q         = (const int*)d_in[0];
    const float* in_scale    = (const float*)d_in[1];
    const int*   w_qkv       = (const int*)d_in[2];
    const float* w_qkv_scale = (const float*)d_in[3];
    const float* b_qkv       = (const float*)d_in[4];
    const int*   w_out       = (const int*)d_in[5];
    const float* w_out_scale = (const float*)d_in[6];
    const float* b_out       = (const float*)d_in[7];
    float* out = (float*)d_out;

    char* ws = (char*)d_ws;
    signed char* x_i8  = (signed char*)(ws);                 // 10,485,760 (dead after GEMM1)
    signed char* wq_i8 = (signed char*)(ws + 10485760);      //  4,915,200 (dead after GEMM1)
    __half* attn_f     = (__half*)(ws);                      // 20,971,520 (overlays x+wq)
    signed char* wo_i8 = (signed char*)(ws + 20971520);      //  1,638,400 (live till GEMM2)
    float*  a_s        = (float*)(ws + 22609920);            //     32,768
    __half* qh_f       = (__half*)(ws + 22642688);           // 20,971,520 [B,H,S,D]
    __half* ql_f       = (__half*)(ws + 43614208);           // 20,971,520
    __half* kh_f       = (__half*)(ws + 64585728);           // 20,971,520
    __half* kl_f       = (__half*)(ws + 85557248);           // 20,971,520
    __half* vt_f       = (__half*)(ws + 106528768);          // 20,971,520 [B,H,D,S]
    signed char* aq_i8 = (signed char*)(ws + 22642688);      // 10,485,760 (overlays qh_f)

    cvt8_all_kernel<<<(NX4 + NQ4 + NO4 + 255) / 256, 256, 0, stream>>>(
        x_q, w_qkv, w_out, (int*)x_i8, (int*)wq_i8, (int*)wo_i8);

    gemm_i8_kernel<<<(T_ / 128) * (QKV_ / 128), 256, 0, stream>>>(
        x_i8, wq_i8, T_, QKV_, E_, in_scale, w_qkv_scale, b_qkv, 0,
        qh_f, ql_f, kh_f, kl_f, vt_f, nullptr);

    attn_kernel<<<B_ * H_ * (S_ / 128), 256, 0, stream>>>(qh_f, ql_f, kh_f, kl_f, vt_f, attn_f);

    requant_kernel<<<T_, 256, 0, stream>>>(attn_f, aq_i8, a_s);

    gemm_i8_kernel<<<(T_ / 128) * (E_ / 128), 256, 0, stream>>>(
        aq_i8, wo_i8, T_, E_, E_, a_s, w_out_scale, b_out, 1,
        nullptr, nullptr, nullptr, nullptr, nullptr, out);
}

// Round 12
// 242.044 us; speedup vs baseline: 1.8733x; 1.0359x over previous
//
#include <hip/hip_runtime.h>
#include <hip/hip_bf16.h>
#include <hip/hip_fp16.h>

typedef __attribute__((ext_vector_type(4))) float f32x4;
typedef __attribute__((ext_vector_type(16))) float f32x16;
typedef __attribute__((ext_vector_type(8))) _Float16 f16x8;
typedef __attribute__((ext_vector_type(2))) __fp16 hf16x2;
typedef __attribute__((ext_vector_type(4))) int i32x4;
typedef __attribute__((ext_vector_type(2))) unsigned int u32x2;

#define B_   8
#define S_   1024
#define H_   20
#define D_   64
#define E_   1280
#define QKV_ 3840
#define T_   8192

#define EXP2F(x) __builtin_amdgcn_exp2f(x)
#define QSCL 0.1803368801111204f   /* 0.125 * log2(e) */

__device__ __forceinline__ void gload_lds16(const void* g, void* l) {
    __builtin_amdgcn_global_load_lds((const __attribute__((address_space(1))) int*)g,
                                     (__attribute__((address_space(3))) int*)l, 16, 0, 0);
}

__device__ __forceinline__ f32x16 zero16() {
    f32x16 z;
#pragma unroll
    for (int i = 0; i < 16; ++i) z[i] = 0.f;
    return z;
}

union pk8 { unsigned int u[4]; f16x8 v; };

// ---------------- int32 -> int8 pack, 3 tensors in one launch ----------------
#define NX4 (T_ * E_ / 4)
#define NQ4 (QKV_ * E_ / 4)
#define NO4 (E_ * E_ / 4)
__global__ __launch_bounds__(256) void cvt8_all_kernel(
    const int* __restrict__ x, const int* __restrict__ wq, const int* __restrict__ wo,
    int* __restrict__ xo, int* __restrict__ wqo, int* __restrict__ woo) {
    int i = blockIdx.x * 256 + threadIdx.x;
    const int* src; int* dst; int idx;
    if (i < NX4)              { src = x;  dst = xo;  idx = i; }
    else if (i < NX4 + NQ4)   { src = wq; dst = wqo; idx = i - NX4; }
    else if (i < NX4+NQ4+NO4) { src = wo; dst = woo; idx = i - NX4 - NQ4; }
    else return;
    i32x4 v = ((const i32x4*)src)[idx];
    dst[idx] = (v[0] & 255) | ((v[1] & 255) << 8) | ((v[2] & 255) << 16) | (v[3] << 24);
}

// ---------------- i8 GEMM: C[M,N] = A[M,K] * B[N,K]^T (i32 accum, exact) -------------
// 128x128 tile, BK=128, global_load_lds w16, 8-slot XOR swizzle, fused dequant epi.
__global__ __launch_bounds__(256) void gemm_i8_kernel(
    const signed char* __restrict__ A, const signed char* __restrict__ Bw,
    int M, int N, int K,
    const float* __restrict__ rowscale, const float* __restrict__ colscale,
    const float* __restrict__ bias, int epilogue,
    __half* __restrict__ qh_out, __half* __restrict__ ql_out,
    __half* __restrict__ kh_out, __half* __restrict__ kl_out,
    __half* __restrict__ vt_out, float* __restrict__ out)
{
    __shared__ signed char As[128 * 128];
    __shared__ signed char Bs[128 * 128];

    const int tid  = threadIdx.x;
    const int lane = tid & 63;
    const int wave = tid >> 6;
    const int wm = wave >> 1, wn = wave & 1;
    const int nTn = N >> 7;
    const int nwg = (M >> 7) * nTn;                   // multiple of 8 for our shapes
    const int swz = (blockIdx.x & 7) * (nwg >> 3) + (blockIdx.x >> 3);
    const int tm = swz / nTn, tn = swz % nTn;

    i32x4 acc[4][4] = {};

    const size_t abase = (size_t)(tm * 128) * K;
    const size_t bbase = (size_t)(tn * 128) * K;

    const int fr = lane & 15;
    const int fg = lane >> 4;

    for (int k0 = 0; k0 < K; k0 += 128) {
        __syncthreads();
#pragma unroll
        for (int c = 0; c < 4; ++c) {
            const int t16 = c * 256 + tid;
            const int row = t16 >> 3;
            const int gsl = ((t16 & 7) ^ (row & 7)) << 4;   // inverse-swizzled global slot
            gload_lds16(A  + abase + (size_t)row * K + k0 + gsl, As + t16 * 16);
            gload_lds16(Bw + bbase + (size_t)row * K + k0 + gsl, Bs + t16 * 16);
        }
        __syncthreads();

#pragma unroll
        for (int kk = 0; kk < 2; ++kk) {
            i32x4 af[4], bf[4];
#pragma unroll
            for (int m = 0; m < 4; ++m)
                af[m] = *(const i32x4*)&As[(wm * 64 + m * 16 + fr) * 128 +
                                           ((((kk << 2) | fg) ^ (fr & 7)) << 4)];
#pragma unroll
            for (int n = 0; n < 4; ++n)
                bf[n] = *(const i32x4*)&Bs[(wn * 64 + n * 16 + fr) * 128 +
                                           ((((kk << 2) | fg) ^ (fr & 7)) << 4)];
            __builtin_amdgcn_s_setprio(1);
#pragma unroll
            for (int m = 0; m < 4; ++m)
#pragma unroll
                for (int n = 0; n < 4; ++n)
                    acc[m][n] = __builtin_amdgcn_mfma_i32_16x16x64_i8(af[m], bf[n], acc[m][n], 0, 0, 0);
            __builtin_amdgcn_s_setprio(0);
        }
    }

    // epilogue: row = tm*128 + wm*64 + m*16 + fg*4 + r ; col = tn*128 + wn*64 + n*16 + fr
#pragma unroll
    for (int m = 0; m < 4; ++m) {
#pragma unroll
        for (int r = 0; r < 4; ++r) {
            const int grow = tm * 128 + wm * 64 + m * 16 + fg * 4 + r;
            const float rs = rowscale[grow];
#pragma unroll
            for (int n = 0; n < 4; ++n) {
                const int gcol = tn * 128 + wn * 64 + n * 16 + fr;
                const float v = (float)acc[m][n][r] * (rs * colscale[gcol]) + bias[gcol];
                if (epilogue == 0) {
                    const int b = grow >> 10, s = grow & 1023;
                    if (gcol < E_) {
                        const float vq = v * QSCL;
                        const __half vh = (__half)vq;
                        const __half vl = (__half)(vq - (float)vh);
                        const int h = gcol >> 6, d = gcol & 63;
                        const size_t idx = (((size_t)(b * H_ + h) << 10) + s) * 64 + d;
                        qh_out[idx] = vh; ql_out[idx] = vl;
                    } else if (gcol < 2 * E_) {
                        const __half vh = (__half)v;
                        const __half vl = (__half)(v - (float)vh);
                        const int o = gcol - E_, h = o >> 6, d = o & 63;
                        const size_t idx = (((size_t)(b * H_ + h) << 10) + s) * 64 + d;
                        kh_out[idx] = vh; kl_out[idx] = vl;
                    } else {
                        const int o = gcol - 2 * E_, h = o >> 6, d = o & 63;
                        vt_out[(((size_t)(b * H_ + h) * 64 + d) << 10) + s] = (__half)v;
                    }
                } else {
                    out[(size_t)grow * E_ + gcol] = v;
                }
            }
        }
    }
}

// ---------------- flash attention v3: 32x32 swapped QK, in-register softmax ----------
// 4 waves x 32 q-rows = 128 q/block; grid 1280 (XCD-clustered).
// st/o are S^T/O^T: col = lane&31 = q -> softmax & rescale lane-local (T12 pattern).
// NOTE: unconditional o-rescale (defer-max T13 measured -11us HERE: branch serializes exp2 chain).
__global__ __launch_bounds__(256) void attn_kernel(
    const __half* __restrict__ Qh, const __half* __restrict__ Ql,
    const __half* __restrict__ Kh, const __half* __restrict__ Kl,
    const __half* __restrict__ VT, __half* __restrict__ attn)
{
    __shared__ char SM[32768];   // K dbuf: Kh[2][64][128B] @0, Kl[2][64][128B] @16384
    const int tid = threadIdx.x, lane = tid & 63, wave = tid >> 6;
    const int L = blockIdx.x;
    const int sIdx = L >> 3;
    const int bh = (L & 7) * 20 + (sIdx >> 3);   // xcd-clustered heads
    const int qt = sIdx & 7;
    const int b = bh / H_, h = bh % H_;
    const int q0 = qt * 128 + wave * 32;
    const size_t base_sd = (size_t)bh * S_ * D_;
    const size_t base_ds = (size_t)bh * D_ * S_;
    const int qL = lane & 31, hi = lane >> 5;

#define KHbuf(bf) ((char*)SM + (bf) * 8192)
#define KLbuf(bf) ((char*)SM + 16384 + (bf) * 8192)

    // Q B-frags: B[d][q]: lane = q, d = s*16 + hi*8 + j
    f16x8 qhf[4], qlf[4];
#pragma unroll
    for (int s = 0; s < 4; ++s) {
        const size_t qa = base_sd + (size_t)(q0 + qL) * 64 + s * 16 + hi * 8;
        qhf[s] = *(const f16x8*)&Qh[qa];
        qlf[s] = *(const f16x8*)&Ql[qa];
    }

    f32x16 o0 = zero16(), o1 = zero16();
    float mrow = -INFINITY, lrow = 0.f;   // per-lane: ONE q-row (q0 + qL)

#define STAGEK(bf, kt) do {                                                   \
    _Pragma("unroll")                                                         \
    for (int c_ = 0; c_ < 2; ++c_) {                                          \
        const int qb_ = c_ * 4096 + tid * 16;                                 \
        const int row_ = qb_ >> 7, cb_ = qb_ & 127;                           \
        const int scb_ = cb_ ^ ((row_ & 7) << 4);                             \
        gload_lds16((const char*)(Kh + base_sd) + (size_t)((kt) + row_) * 128 + scb_, \
                    KHbuf(bf) + qb_);                                         \
        gload_lds16((const char*)(Kl + base_sd) + (size_t)((kt) + row_) * 128 + scb_, \
                    KLbuf(bf) + qb_);                                         \
    }                                                                         \
} while (0)

// QK on one 32-k tile: score^T = Kh*Qh + Kl*Qh + Kh*Ql
#define QKTILE(ST, KT2) do {                                                  \
    _Pragma("unroll")                                                         \
    for (int s_ = 0; s_ < 4; ++s_) {                                          \
        const int row_ = (KT2) * 32 + qL;                                     \
        const int off_ = row_ * 128 + ((s_ * 32 + hi * 16) ^ ((row_ & 7) << 4)); \
        f16x8 ah_ = *(const f16x8*)(KHbuf(bf) + off_);                        \
        f16x8 al_ = *(const f16x8*)(KLbuf(bf) + off_);                        \
        ST = __builtin_amdgcn_mfma_f32_32x32x16_f16(ah_, qhf[s_], ST, 0, 0, 0); \
        ST = __builtin_amdgcn_mfma_f32_32x32x16_f16(al_, qhf[s_], ST, 0, 0, 0); \
        ST = __builtin_amdgcn_mfma_f32_32x32x16_f16(ah_, qlf[s_], ST, 0, 0, 0); \
    }                                                                         \
} while (0)

// pack exp'd ST (16 f32) into two PV B-frags via cvt_pkrtz + permlane32_swap (T12)
#define PACKP(ST, BF0, BF1) do {                                              \
    unsigned pk_[8];                                                          \
    _Pragma("unroll")                                                         \
    for (int j_ = 0; j_ < 8; ++j_) {                                          \
        union { hf16x2 h; unsigned u; } cv_;                                  \
        cv_.h = __builtin_amdgcn_cvt_pkrtz(ST[2 * j_], ST[2 * j_ + 1]);       \
        pk_[j_] = cv_.u;                                                      \
    }                                                                         \
    u32x2 rA_ = __builtin_amdgcn_permlane32_swap(pk_[0], pk_[2], false, false); \
    u32x2 rB_ = __builtin_amdgcn_permlane32_swap(pk_[1], pk_[3], false, false); \
    BF0.u[0] = rA_[0]; BF0.u[1] = rB_[0]; BF0.u[2] = rA_[1]; BF0.u[3] = rB_[1]; \
    u32x2 rC_ = __builtin_amdgcn_permlane32_swap(pk_[4], pk_[6], false, false); \
    u32x2 rD_ = __builtin_amdgcn_permlane32_swap(pk_[5], pk_[7], false, false); \
    BF1.u[0] = rC_[0]; BF1.u[1] = rD_[0]; BF1.u[2] = rC_[1]; BF1.u[3] = rD_[1]; \
} while (0)

    STAGEK(0, 0);
    __syncthreads();

    for (int it = 0; it < 16; ++it) {
        const int kt = it * 64, bf = it & 1;
        if (it < 15) STAGEK(bf ^ 1, kt + 64);

        // V^T A-frags: A[d][k]: lane = d, k = ks*16 + hi*8 + j  (direct row-major loads)
        f16x8 vf0[4], vf1[4];
#pragma unroll
        for (int ks = 0; ks < 4; ++ks) {
            const size_t va = base_ds + (size_t)qL * S_ + kt + ks * 16 + hi * 8;
            vf0[ks] = *(const f16x8*)&VT[va];
            vf1[ks] = *(const f16x8*)&VT[va + (size_t)32 * S_];
        }

        f32x16 st0 = zero16(), st1 = zero16();
        __builtin_amdgcn_s_setprio(1);
        QKTILE(st0, 0);
        QKTILE(st1, 1);
        __builtin_amdgcn_s_setprio(0);

        // softmax: lane holds 32 of the 64 k for its q; partner (lane^32) the rest
        float mx = -INFINITY;
#pragma unroll
        for (int r = 0; r < 16; ++r) { mx = fmaxf(mx, st0[r]); mx = fmaxf(mx, st1[r]); }
        mx = fmaxf(mx, __shfl_xor(mx, 32));
        const float mn = fmaxf(mrow, mx);
        const float fsc = EXP2F(mrow - mn);   // exp2(-inf)=0 first tile
        mrow = mn;
        lrow *= fsc;
#pragma unroll
        for (int r = 0; r < 16; ++r) { o0[r] *= fsc; o1[r] *= fsc; }

        float rsum = 0.f;
#pragma unroll
        for (int r = 0; r < 16; ++r) { st0[r] = EXP2F(st0[r] - mn); rsum += st0[r]; }
#pragma unroll
        for (int r = 0; r < 16; ++r) { st1[r] = EXP2F(st1[r] - mn); rsum += st1[r]; }
        rsum += __shfl_xor(rsum, 32);
        lrow += rsum;

        // P -> f16 B-frags, fully in-register
        pk8 Bf0, Bf1, Bf2, Bf3;
        PACKP(st0, Bf0, Bf1);
        PACKP(st1, Bf2, Bf3);

        __builtin_amdgcn_s_setprio(1);
        o0 = __builtin_amdgcn_mfma_f32_32x32x16_f16(vf0[0], Bf0.v, o0, 0, 0, 0);
        o0 = __builtin_amdgcn_mfma_f32_32x32x16_f16(vf0[1], Bf1.v, o0, 0, 0, 0);
        o0 = __builtin_amdgcn_mfma_f32_32x32x16_f16(vf0[2], Bf2.v, o0, 0, 0, 0);
        o0 = __builtin_amdgcn_mfma_f32_32x32x16_f16(vf0[3], Bf3.v, o0, 0, 0, 0);
        o1 = __builtin_amdgcn_mfma_f32_32x32x16_f16(vf1[0], Bf0.v, o1, 0, 0, 0);
        o1 = __builtin_amdgcn_mfma_f32_32x32x16_f16(vf1[1], Bf1.v, o1, 0, 0, 0);
        o1 = __builtin_amdgcn_mfma_f32_32x32x16_f16(vf1[2], Bf2.v, o1, 0, 0, 0);
        o1 = __builtin_amdgcn_mfma_f32_32x32x16_f16(vf1[3], Bf3.v, o1, 0, 0, 0);
        __builtin_amdgcn_s_setprio(0);

        __syncthreads();
    }

    // epilogue: O^T -> LDS transpose (per-wave region over dead K LDS) -> coalesced f16
    const float inv = 1.f / lrow;
    float* ob = (float*)((char*)SM + wave * 4224);   // [32][33] f32
#pragma unroll
    for (int dt = 0; dt < 2; ++dt) {
#pragma unroll
        for (int r = 0; r < 16; ++r) {
            const int dl = (r & 3) + 8 * (r >> 2) + 4 * hi;
            ob[qL * 33 + dl] = (dt ? o1[r] : o0[r]) * inv;
        }
        asm volatile("s_waitcnt lgkmcnt(0)" ::: "memory");
        __builtin_amdgcn_sched_barrier(0);
        f16x8 w0, w1;
#pragma unroll
        for (int j = 0; j < 8; ++j) {
            w0[j] = (_Float16)ob[qL * 33 + hi * 16 + j];
            w1[j] = (_Float16)ob[qL * 33 + hi * 16 + 8 + j];
        }
        __half* dst = attn + (size_t)((b << 10) + q0 + qL) * E_ + h * 64 + dt * 32 + hi * 16;
        *(f16x8*)dst = w0;
        *(f16x8*)(dst + 8) = w1;
        asm volatile("s_waitcnt lgkmcnt(0)" ::: "memory");
        __builtin_amdgcn_sched_barrier(0);
    }
#undef STAGEK
#undef QKTILE
#undef PACKP
#undef KHbuf
#undef KLbuf
}

// ---------------- per-token symmetric int8 requant (int8 output for i8 GEMM) ---------
__global__ __launch_bounds__(256) void requant_kernel(
    const __half* __restrict__ attn, signed char* __restrict__ aq, float* __restrict__ as_)
{
    const int t = blockIdx.x;
    const int tid = threadIdx.x;
    __shared__ float red[4];
    const __half* row = attn + (size_t)t * E_;
    float x[5];
    float amax = 0.f;
#pragma unroll
    for (int j = 0; j < 5; ++j) {
        x[j] = (float)row[tid + j * 256];
        amax = fmaxf(amax, fabsf(x[j]));
    }
#pragma unroll
    for (int off = 1; off < 64; off <<= 1) amax = fmaxf(amax, __shfl_xor(amax, off));
    if ((tid & 63) == 0) red[tid >> 6] = amax;
    __syncthreads();
    amax = fmaxf(fmaxf(red[0], red[1]), fmaxf(red[2], red[3]));
    const float s = fmaxf(amax / 127.f, 1e-8f);
    if (tid == 0) as_[t] = s;
#pragma unroll
    for (int j = 0; j < 5; ++j) {
        float qv = fminf(fmaxf(rintf(x[j] / s), -127.f), 127.f);
        aq[(size_t)t * E_ + tid + j * 256] = (signed char)(int)qv;
    }
}

// ---------------- launch ----------------
extern "C" void kernel_launch(void* const* d_in, const int* in_sizes, int n_in,
                              void* d_out, int out_size, void* d_ws, size_t ws_size,
                              hipStream_t stream) {
    const int*   x_q         = (const int*)d_in[0];
    const float* in_scale    = (const float*)d_in[1];
    const int*   w_qkv       = (const int*)d_in[2];
    const float* w_qkv_scale = (const float*)d_in[3];
    const float* b_qkv       = (const float*)d_in[4];
    const int*   w_out       = (const int*)d_in[5];
    const float* w_out_scale = (const float*)d_in[6];
    const float* b_out       = (const float*)d_in[7];
    float* out = (float*)d_out;

    char* ws = (char*)d_ws;
    signed char* x_i8  = (signed char*)(ws);                 // 10,485,760 (dead after GEMM1)
    signed char* wq_i8 = (signed char*)(ws + 10485760);      //  4,915,200 (dead after GEMM1)
    __half* attn_f     = (__half*)(ws);                      // 20,971,520 (overlays x+wq)
    signed char* wo_i8 = (signed char*)(ws + 20971520);      //  1,638,400 (live till GEMM2)
    float*  a_s        = (float*)(ws + 22609920);            //     32,768
    __half* qh_f       = (__half*)(ws + 22642688);           // 20,971,520 [B,H,S,D]
    __half* ql_f       = (__half*)(ws + 43614208);           // 20,971,520
    __half* kh_f       = (__half*)(ws + 64585728);           // 20,971,520
    __half* kl_f       = (__half*)(ws + 85557248);           // 20,971,520
    __half* vt_f       = (__half*)(ws + 106528768);          // 20,971,520 [B,H,D,S]
    signed char* aq_i8 = (signed char*)(ws + 22642688);      // 10,485,760 (overlays qh_f)

    cvt8_all_kernel<<<(NX4 + NQ4 + NO4 + 255) / 256, 256, 0, stream>>>(
        x_q, w_qkv, w_out, (int*)x_i8, (int*)wq_i8, (int*)wo_i8);

    gemm_i8_kernel<<<(T_ / 128) * (QKV_ / 128), 256, 0, stream>>>(
        x_i8, wq_i8, T_, QKV_, E_, in_scale, w_qkv_scale, b_qkv, 0,
        qh_f, ql_f, kh_f, kl_f, vt_f, nullptr);

    attn_kernel<<<B_ * H_ * (S_ / 128), 256, 0, stream>>>(qh_f, ql_f, kh_f, kl_f, vt_f, attn_f);

    requant_kernel<<<T_, 256, 0, stream>>>(attn_f, aq_i8, a_s);

    gemm_i8_kernel<<<(T_ / 128) * (E_ / 128), 256, 0, stream>>>(
        aq_i8, wo_i8, T_, E_, E_, a_s, w_out_scale, b_out, 1,
        nullptr, nullptr, nullptr, nullptr, nullptr, out);
}

// Round 13
// 236.805 us; speedup vs baseline: 1.9147x; 1.0221x over previous
//
#include <hip/hip_runtime.h>
#include <hip/hip_bf16.h>
#include <hip/hip_fp16.h>

typedef __attribute__((ext_vector_type(4))) float f32x4;
typedef __attribute__((ext_vector_type(16))) float f32x16;
typedef __attribute__((ext_vector_type(8))) _Float16 f16x8;
typedef __attribute__((ext_vector_type(2))) __fp16 hf16x2;
typedef __attribute__((ext_vector_type(4))) int i32x4;
typedef __attribute__((ext_vector_type(2))) unsigned int u32x2;

#define B_   8
#define S_   1024
#define H_   20
#define D_   64
#define E_   1280
#define QKV_ 3840
#define T_   8192

#define EXP2F(x) __builtin_amdgcn_exp2f(x)
#define QSCL 0.1803368801111204f   /* 0.125 * log2(e) */

__device__ __forceinline__ void gload_lds16(const void* g, void* l) {
    __builtin_amdgcn_global_load_lds((const __attribute__((address_space(1))) int*)g,
                                     (__attribute__((address_space(3))) int*)l, 16, 0, 0);
}

__device__ __forceinline__ f32x16 zero16() {
    f32x16 z;
#pragma unroll
    for (int i = 0; i < 16; ++i) z[i] = 0.f;
    return z;
}

union pk8 { unsigned int u[4]; f16x8 v; };

// ---------------- int32 -> int8 pack, 3 tensors, 16 elems/thread ----------------
#define NX16 (T_ * E_ / 16)
#define NQ16 (QKV_ * E_ / 16)
#define NO16 (E_ * E_ / 16)
__device__ __forceinline__ int pack4(i32x4 v) {
    return (v[0] & 255) | ((v[1] & 255) << 8) | ((v[2] & 255) << 16) | (v[3] << 24);
}
__global__ __launch_bounds__(256) void cvt8_all_kernel(
    const int* __restrict__ x, const int* __restrict__ wq, const int* __restrict__ wo,
    int* __restrict__ xo, int* __restrict__ wqo, int* __restrict__ woo) {
    int i = blockIdx.x * 256 + threadIdx.x;
    const int* src; int* dst; int idx;
    if (i < NX16)                { src = x;  dst = xo;  idx = i; }
    else if (i < NX16 + NQ16)    { src = wq; dst = wqo; idx = i - NX16; }
    else if (i < NX16+NQ16+NO16) { src = wo; dst = woo; idx = i - NX16 - NQ16; }
    else return;
    const i32x4* s4 = (const i32x4*)src + idx * 4;
    i32x4 o;
    o[0] = pack4(s4[0]); o[1] = pack4(s4[1]); o[2] = pack4(s4[2]); o[3] = pack4(s4[3]);
    ((i32x4*)dst)[idx] = o;
}

// ---------------- i8 GEMM: C[M,N] = A[M,K] * B[N,K]^T (i32 accum, exact) -------------
// 128x128 tile, BK=128, global_load_lds w16, 8-slot XOR swizzle, fused dequant epi.
__global__ __launch_bounds__(256) void gemm_i8_kernel(
    const signed char* __restrict__ A, const signed char* __restrict__ Bw,
    int M, int N, int K,
    const float* __restrict__ rowscale, const float* __restrict__ colscale,
    const float* __restrict__ bias, int epilogue,
    __half* __restrict__ qh_out, __half* __restrict__ ql_out,
    __half* __restrict__ kh_out, __half* __restrict__ kl_out,
    __half* __restrict__ vt_out, float* __restrict__ out)
{
    __shared__ signed char As[128 * 128];
    __shared__ signed char Bs[128 * 128];

    const int tid  = threadIdx.x;
    const int lane = tid & 63;
    const int wave = tid >> 6;
    const int wm = wave >> 1, wn = wave & 1;
    const int nTn = N >> 7;
    const int nwg = (M >> 7) * nTn;                   // multiple of 8 for our shapes
    const int swz = (blockIdx.x & 7) * (nwg >> 3) + (blockIdx.x >> 3);
    const int tm = swz / nTn, tn = swz % nTn;

    i32x4 acc[4][4] = {};

    const size_t abase = (size_t)(tm * 128) * K;
    const size_t bbase = (size_t)(tn * 128) * K;

    const int fr = lane & 15;
    const int fg = lane >> 4;

    for (int k0 = 0; k0 < K; k0 += 128) {
        __syncthreads();
#pragma unroll
        for (int c = 0; c < 4; ++c) {
            const int t16 = c * 256 + tid;
            const int row = t16 >> 3;
            const int gsl = ((t16 & 7) ^ (row & 7)) << 4;   // inverse-swizzled global slot
            gload_lds16(A  + abase + (size_t)row * K + k0 + gsl, As + t16 * 16);
            gload_lds16(Bw + bbase + (size_t)row * K + k0 + gsl, Bs + t16 * 16);
        }
        __syncthreads();

#pragma unroll
        for (int kk = 0; kk < 2; ++kk) {
            i32x4 af[4], bf[4];
#pragma unroll
            for (int m = 0; m < 4; ++m)
                af[m] = *(const i32x4*)&As[(wm * 64 + m * 16 + fr) * 128 +
                                           ((((kk << 2) | fg) ^ (fr & 7)) << 4)];
#pragma unroll
            for (int n = 0; n < 4; ++n)
                bf[n] = *(const i32x4*)&Bs[(wn * 64 + n * 16 + fr) * 128 +
                                           ((((kk << 2) | fg) ^ (fr & 7)) << 4)];
            __builtin_amdgcn_s_setprio(1);
#pragma unroll
            for (int m = 0; m < 4; ++m)
#pragma unroll
                for (int n = 0; n < 4; ++n)
                    acc[m][n] = __builtin_amdgcn_mfma_i32_16x16x64_i8(af[m], bf[n], acc[m][n], 0, 0, 0);
            __builtin_amdgcn_s_setprio(0);
        }
    }

    // epilogue: row = tm*128 + wm*64 + m*16 + fg*4 + r ; col = tn*128 + wn*64 + n*16 + fr
#pragma unroll
    for (int m = 0; m < 4; ++m) {
#pragma unroll
        for (int r = 0; r < 4; ++r) {
            const int grow = tm * 128 + wm * 64 + m * 16 + fg * 4 + r;
            const float rs = rowscale[grow];
#pragma unroll
            for (int n = 0; n < 4; ++n) {
                const int gcol = tn * 128 + wn * 64 + n * 16 + fr;
                const float v = (float)acc[m][n][r] * (rs * colscale[gcol]) + bias[gcol];
                if (epilogue == 0) {
                    const int b = grow >> 10, s = grow & 1023;
                    if (gcol < E_) {
                        const float vq = v * QSCL;
                        const __half vh = (__half)vq;
                        const __half vl = (__half)(vq - (float)vh);
                        const int h = gcol >> 6, d = gcol & 63;
                        const size_t idx = (((size_t)(b * H_ + h) << 10) + s) * 64 + d;
                        qh_out[idx] = vh; ql_out[idx] = vl;
                    } else if (gcol < 2 * E_) {
                        const __half vh = (__half)v;
                        const __half vl = (__half)(v - (float)vh);
                        const int o = gcol - E_, h = o >> 6, d = o & 63;
                        const size_t idx = (((size_t)(b * H_ + h) << 10) + s) * 64 + d;
                        kh_out[idx] = vh; kl_out[idx] = vl;
                    } else {
                        const int o = gcol - 2 * E_, h = o >> 6, d = o & 63;
                        vt_out[(((size_t)(b * H_ + h) * 64 + d) << 10) + s] = (__half)v;
                    }
                } else {
                    out[(size_t)grow * E_ + gcol] = v;
                }
            }
        }
    }
}

// ---------------- flash attention v4: v3 + reg-diet (ql->LDS, vf split) + trees ------
// 4 waves x 32 q-rows = 128 q/block; grid 1280 (XCD-clustered); target 3 waves/SIMD.
__global__ __launch_bounds__(256, 3) void attn_kernel(
    const __half* __restrict__ Qh, const __half* __restrict__ Ql,
    const __half* __restrict__ Kh, const __half* __restrict__ Kl,
    const __half* __restrict__ VT, __half* __restrict__ attn)
{
    __shared__ char SM[49152];   // Kh dbuf @0 (16KB), Kl dbuf @16384 (16KB), QL @32768 (16KB)
    const int tid = threadIdx.x, lane = tid & 63, wave = tid >> 6;
    const int L = blockIdx.x;
    const int sIdx = L >> 3;
    const int bh = (L & 7) * 20 + (sIdx >> 3);   // xcd-clustered heads
    const int qt = sIdx & 7;
    const int b = bh / H_, h = bh % H_;
    const int q0 = qt * 128 + wave * 32;
    const size_t base_sd = (size_t)bh * S_ * D_;
    const size_t base_ds = (size_t)bh * D_ * S_;
    const int qL = lane & 31, hi = lane >> 5;

#define KHbuf(bf) ((char*)SM + (bf) * 8192)
#define KLbuf(bf) ((char*)SM + 16384 + (bf) * 8192)

    // Q hi frags stay in regs: B[d][q]: lane = q, d = s*16 + hi*8 + j
    f16x8 qhf[4];
#pragma unroll
    for (int s = 0; s < 4; ++s)
        qhf[s] = *(const f16x8*)&Qh[base_sd + (size_t)(q0 + qL) * 64 + s * 16 + hi * 8];

    // Q lo frags -> per-wave LDS (slot-XOR: 8 lanes/bank-group = optimal)
    int qlb = 32768 + wave * 4096 + qL * 128;
#pragma unroll
    for (int s = 0; s < 4; ++s) {
        f16x8 qlv = *(const f16x8*)&Ql[base_sd + (size_t)(q0 + qL) * 64 + s * 16 + hi * 8];
        *(f16x8*)(SM + qlb + ((((s << 1) | hi) ^ (qL & 7)) << 4)) = qlv;
    }

    f32x16 o0 = zero16(), o1 = zero16();
    float mrow = -INFINITY, lrow = 0.f;   // per-lane: ONE q-row (q0 + qL)

#define STAGEK(bf, kt) do {                                                   \
    _Pragma("unroll")                                                         \
    for (int c_ = 0; c_ < 2; ++c_) {                                          \
        const int qb_ = c_ * 4096 + tid * 16;                                 \
        const int row_ = qb_ >> 7, cb_ = qb_ & 127;                           \
        const int scb_ = cb_ ^ ((row_ & 7) << 4);                             \
        gload_lds16((const char*)(Kh + base_sd) + (size_t)((kt) + row_) * 128 + scb_, \
                    KHbuf(bf) + qb_);                                         \
        gload_lds16((const char*)(Kl + base_sd) + (size_t)((kt) + row_) * 128 + scb_, \
                    KLbuf(bf) + qb_);                                         \
    }                                                                         \
} while (0)

// QK on one 32-k tile: score^T = Kh*Qh + Kl*Qh + Kh*Ql (ql frag from LDS)
#define QKTILE(ST, KT2) do {                                                  \
    _Pragma("unroll")                                                         \
    for (int s_ = 0; s_ < 4; ++s_) {                                          \
        const int row_ = (KT2) * 32 + qL;                                     \
        const int off_ = row_ * 128 + ((s_ * 32 + hi * 16) ^ ((row_ & 7) << 4)); \
        f16x8 ah_ = *(const f16x8*)(KHbuf(bf) + off_);                        \
        f16x8 al_ = *(const f16x8*)(KLbuf(bf) + off_);                        \
        f16x8 ql_ = *(const f16x8*)(SM + qlb + ((((s_ << 1) | hi) ^ (qL & 7)) << 4)); \
        ST = __builtin_amdgcn_mfma_f32_32x32x16_f16(ah_, qhf[s_], ST, 0, 0, 0); \
        ST = __builtin_amdgcn_mfma_f32_32x32x16_f16(al_, qhf[s_], ST, 0, 0, 0); \
        ST = __builtin_amdgcn_mfma_f32_32x32x16_f16(ah_, ql_, ST, 0, 0, 0);  \
    }                                                                         \
} while (0)

// pack exp'd ST (16 f32) into two PV B-frags via cvt_pkrtz + permlane32_swap (T12)
#define PACKP(ST, BF0, BF1) do {                                              \
    unsigned pk_[8];                                                          \
    _Pragma("unroll")                                                         \
    for (int j_ = 0; j_ < 8; ++j_) {                                          \
        union { hf16x2 h; unsigned u; } cv_;                                  \
        cv_.h = __builtin_amdgcn_cvt_pkrtz(ST[2 * j_], ST[2 * j_ + 1]);       \
        pk_[j_] = cv_.u;                                                      \
    }                                                                         \
    u32x2 rA_ = __builtin_amdgcn_permlane32_swap(pk_[0], pk_[2], false, false); \
    u32x2 rB_ = __builtin_amdgcn_permlane32_swap(pk_[1], pk_[3], false, false); \
    BF0.u[0] = rA_[0]; BF0.u[1] = rB_[0]; BF0.u[2] = rA_[1]; BF0.u[3] = rB_[1]; \
    u32x2 rC_ = __builtin_amdgcn_permlane32_swap(pk_[4], pk_[6], false, false); \
    u32x2 rD_ = __builtin_amdgcn_permlane32_swap(pk_[5], pk_[7], false, false); \
    BF1.u[0] = rC_[0]; BF1.u[1] = rD_[0]; BF1.u[2] = rC_[1]; BF1.u[3] = rD_[1]; \
} while (0)

    STAGEK(0, 0);
    __syncthreads();

    for (int it = 0; it < 16; ++it) {
        const int kt = it * 64, bf = it & 1;
        asm volatile("" : "+v"(qlb));    // defeat loop-invariant hoisting of ql reads
        if (it < 15) STAGEK(bf ^ 1, kt + 64);

        // V^T A-frags, first d-half only (second half loaded after QK: -16 VGPR in QK phase)
        f16x8 vf0[4];
#pragma unroll
        for (int ks = 0; ks < 4; ++ks)
            vf0[ks] = *(const f16x8*)&VT[base_ds + (size_t)qL * S_ + kt + ks * 16 + hi * 8];

        f32x16 st0 = zero16(), st1 = zero16();
        __builtin_amdgcn_s_setprio(1);
        QKTILE(st0, 0);
        QKTILE(st1, 1);
        __builtin_amdgcn_s_setprio(0);

        f16x8 vf1[4];
#pragma unroll
        for (int ks = 0; ks < 4; ++ks)
            vf1[ks] = *(const f16x8*)&VT[base_ds + (size_t)(32 + qL) * S_ + kt + ks * 16 + hi * 8];

        // softmax: tree max (depth 5) over this lane's 32, then partner via xor32
        float m8[8];
#pragma unroll
        for (int r = 0; r < 8; ++r)
            m8[r] = fmaxf(fmaxf(st0[2 * r], st0[2 * r + 1]),
                          fmaxf(st1[2 * r], st1[2 * r + 1]));
        float mx = fmaxf(fmaxf(fmaxf(m8[0], m8[1]), fmaxf(m8[2], m8[3])),
                         fmaxf(fmaxf(m8[4], m8[5]), fmaxf(m8[6], m8[7])));
        mx = fmaxf(mx, __shfl_xor(mx, 32));
        const float mn = fmaxf(mrow, mx);
        const float fsc = EXP2F(mrow - mn);   // exp2(-inf)=0 first tile
        mrow = mn;
        lrow *= fsc;
#pragma unroll
        for (int r = 0; r < 16; ++r) { o0[r] *= fsc; o1[r] *= fsc; }

#pragma unroll
        for (int r = 0; r < 16; ++r) { st0[r] = EXP2F(st0[r] - mn); }
#pragma unroll
        for (int r = 0; r < 16; ++r) { st1[r] = EXP2F(st1[r] - mn); }
        // tree rsum (depth 5)
        float r8[8];
#pragma unroll
        for (int r = 0; r < 8; ++r)
            r8[r] = (st0[2 * r] + st0[2 * r + 1]) + (st1[2 * r] + st1[2 * r + 1]);
        float rsum = ((r8[0] + r8[1]) + (r8[2] + r8[3])) + ((r8[4] + r8[5]) + (r8[6] + r8[7]));
        rsum += __shfl_xor(rsum, 32);
        lrow += rsum;

        // P -> f16 B-frags, fully in-register
        pk8 Bf0, Bf1, Bf2, Bf3;
        PACKP(st0, Bf0, Bf1);
        PACKP(st1, Bf2, Bf3);

        __builtin_amdgcn_s_setprio(1);
        o0 = __builtin_amdgcn_mfma_f32_32x32x16_f16(vf0[0], Bf0.v, o0, 0, 0, 0);
        o0 = __builtin_amdgcn_mfma_f32_32x32x16_f16(vf0[1], Bf1.v, o0, 0, 0, 0);
        o0 = __builtin_amdgcn_mfma_f32_32x32x16_f16(vf0[2], Bf2.v, o0, 0, 0, 0);
        o0 = __builtin_amdgcn_mfma_f32_32x32x16_f16(vf0[3], Bf3.v, o0, 0, 0, 0);
        o1 = __builtin_amdgcn_mfma_f32_32x32x16_f16(vf1[0], Bf0.v, o1, 0, 0, 0);
        o1 = __builtin_amdgcn_mfma_f32_32x32x16_f16(vf1[1], Bf1.v, o1, 0, 0, 0);
        o1 = __builtin_amdgcn_mfma_f32_32x32x16_f16(vf1[2], Bf2.v, o1, 0, 0, 0);
        o1 = __builtin_amdgcn_mfma_f32_32x32x16_f16(vf1[3], Bf3.v, o1, 0, 0, 0);
        __builtin_amdgcn_s_setprio(0);

        __syncthreads();
    }

    // epilogue: O^T -> LDS transpose (per-wave region over dead K LDS) -> coalesced f16
    const float inv = 1.f / lrow;
    float* ob = (float*)((char*)SM + wave * 4224);   // [32][33] f32
#pragma unroll
    for (int dt = 0; dt < 2; ++dt) {
#pragma unroll
        for (int r = 0; r < 16; ++r) {
            const int dl = (r & 3) + 8 * (r >> 2) + 4 * hi;
            ob[qL * 33 + dl] = (dt ? o1[r] : o0[r]) * inv;
        }
        asm volatile("s_waitcnt lgkmcnt(0)" ::: "memory");
        __builtin_amdgcn_sched_barrier(0);
        f16x8 w0, w1;
#pragma unroll
        for (int j = 0; j < 8; ++j) {
            w0[j] = (_Float16)ob[qL * 33 + hi * 16 + j];
            w1[j] = (_Float16)ob[qL * 33 + hi * 16 + 8 + j];
        }
        __half* dst = attn + (size_t)((b << 10) + q0 + qL) * E_ + h * 64 + dt * 32 + hi * 16;
        *(f16x8*)dst = w0;
        *(f16x8*)(dst + 8) = w1;
        asm volatile("s_waitcnt lgkmcnt(0)" ::: "memory");
        __builtin_amdgcn_sched_barrier(0);
    }
#undef STAGEK
#undef QKTILE
#undef PACKP
#undef KHbuf
#undef KLbuf
}

// ---------------- per-token symmetric int8 requant (int8 output for i8 GEMM) ---------
__global__ __launch_bounds__(256) void requant_kernel(
    const __half* __restrict__ attn, signed char* __restrict__ aq, float* __restrict__ as_)
{
    const int t = blockIdx.x;
    const int tid = threadIdx.x;
    __shared__ float red[4];
    const __half* row = attn + (size_t)t * E_;
    float x[5];
    float amax = 0.f;
#pragma unroll
    for (int j = 0; j < 5; ++j) {
        x[j] = (float)row[tid + j * 256];
        amax = fmaxf(amax, fabsf(x[j]));
    }
#pragma unroll
    for (int off = 1; off < 64; off <<= 1) amax = fmaxf(amax, __shfl_xor(amax, off));
    if ((tid & 63) == 0) red[tid >> 6] = amax;
    __syncthreads();
    amax = fmaxf(fmaxf(red[0], red[1]), fmaxf(red[2], red[3]));
    const float s = fmaxf(amax / 127.f, 1e-8f);
    if (tid == 0) as_[t] = s;
#pragma unroll
    for (int j = 0; j < 5; ++j) {
        float qv = fminf(fmaxf(rintf(x[j] / s), -127.f), 127.f);
        aq[(size_t)t * E_ + tid + j * 256] = (signed char)(int)qv;
    }
}

// ---------------- launch ----------------
extern "C" void kernel_launch(void* const* d_in, const int* in_sizes, int n_in,
                              void* d_out, int out_size, void* d_ws, size_t ws_size,
                              hipStream_t stream) {
    const int*   x_q         = (const int*)d_in[0];
    const float* in_scale    = (const float*)d_in[1];
    const int*   w_qkv       = (const int*)d_in[2];
    const float* w_qkv_scale = (const float*)d_in[3];
    const float* b_qkv       = (const float*)d_in[4];
    const int*   w_out       = (const int*)d_in[5];
    const float* w_out_scale = (const float*)d_in[6];
    const float* b_out       = (const float*)d_in[7];
    float* out = (float*)d_out;

    char* ws = (char*)d_ws;
    signed char* x_i8  = (signed char*)(ws);                 // 10,485,760 (dead after GEMM1)
    signed char* wq_i8 = (signed char*)(ws + 10485760);      //  4,915,200 (dead after GEMM1)
    __half* attn_f     = (__half*)(ws);                      // 20,971,520 (overlays x+wq)
    signed char* wo_i8 = (signed char*)(ws + 20971520);      //  1,638,400 (live till GEMM2)
    float*  a_s        = (float*)(ws + 22609920);            //     32,768
    __half* qh_f       = (__half*)(ws + 22642688);           // 20,971,520 [B,H,S,D]
    __half* ql_f       = (__half*)(ws + 43614208);           // 20,971,520
    __half* kh_f       = (__half*)(ws + 64585728);           // 20,971,520
    __half* kl_f       = (__half*)(ws + 85557248);           // 20,971,520
    __half* vt_f       = (__half*)(ws + 106528768);          // 20,971,520 [B,H,D,S]
    signed char* aq_i8 = (signed char*)(ws + 22642688);      // 10,485,760 (overlays qh_f)

    cvt8_all_kernel<<<(NX16 + NQ16 + NO16 + 255) / 256, 256, 0, stream>>>(
        x_q, w_qkv, w_out, (int*)x_i8, (int*)wq_i8, (int*)wo_i8);

    gemm_i8_kernel<<<(T_ / 128) * (QKV_ / 128), 256, 0, stream>>>(
        x_i8, wq_i8, T_, QKV_, E_, in_scale, w_qkv_scale, b_qkv, 0,
        qh_f, ql_f, kh_f, kl_f, vt_f, nullptr);

    attn_kernel<<<B_ * H_ * (S_ / 128), 256, 0, stream>>>(qh_f, ql_f, kh_f, kl_f, vt_f, attn_f);

    requant_kernel<<<T_, 256, 0, stream>>>(attn_f, aq_i8, a_s);

    gemm_i8_kernel<<<(T_ / 128) * (E_ / 128), 256, 0, stream>>>(
        aq_i8, wo_i8, T_, E_, E_, a_s, w_out_scale, b_out, 1,
        nullptr, nullptr, nullptr, nullptr, nullptr, out);
}